// Round 8
// baseline (166.623 us; speedup 1.0000x reference)
//
#include <hip/hip_runtime.h>

constexpr int kB = 256;
constexpr int kNC = 99;
constexpr int kN = 100;
constexpr int kC = 128;
constexpr int kH = 512;
constexpr int kL = 3;
constexpr int kNT = kB * kN;   // 25600
constexpr float kEps = 1e-5f;

typedef unsigned short u16;
typedef unsigned int u32;
typedef __attribute__((ext_vector_type(8))) __bf16 bf16x8;
typedef __attribute__((ext_vector_type(4))) float f32x4;

__device__ __forceinline__ u16 f2bf(float x) {
  __bf16 h = (__bf16)x;                 // native v_cvt (RNE), 1 VALU op
  return __builtin_bit_cast(u16, h);
}
__device__ __forceinline__ float bf2f(u16 h) {
  union { u32 u; float f; } v; v.u = ((u32)h) << 16;
  return v.f;
}

// per-channel BN affine from raw (sum, sumsq) stats; stats==nullptr -> identity
__device__ __forceinline__ void affine_from_stats(
    const float* __restrict__ stats, const float* __restrict__ gamma,
    const float* __restrict__ beta, int c, float& sc, float& sh) {
  if (stats != nullptr) {
    float s = stats[c], sq = stats[kC + c];
    float m = s * (1.0f / kNT);
    float v = sq * (1.0f / kNT) - m * m;
    float rs = rsqrtf(v + kEps);
    sc = gamma[c] * rs;
    sh = beta[c] - m * sc;
  } else {
    sc = 1.0f;
    sh = 0.0f;
  }
}

// ---- weight pack (432 blocks) + stats zero.
// pack layout: frag f; lane l; elem j: B[kb*32 + (l>>4)*8 + j][nb*16 + (l&15)]
//   gcn/W1: f = nb*4 + kb ; W2: f = nb*16 + kb
//   per layer: gcn frags [0,32), W1 [32,160), W2 [160,288), each frag 512 u16.
__global__ __launch_bounds__(256) void k_prep(
    const float* __restrict__ gcnW, const float* __restrict__ W1,
    const float* __restrict__ W2, u16* __restrict__ wpack,
    float* __restrict__ stats) {
  if (blockIdx.x == 0) {
    for (int i = threadIdx.x; i < kL * 2 * 2 * kC; i += 256) stats[i] = 0.0f;
  }
  int g = blockIdx.x * 256 + threadIdx.x;          // < 110592 float4-groups
  int layer = g / 36864, r = g % 36864;
  const float* src; int shf; u16* base; int isW2 = 0;
  if (r < 4096) {
    src = gcnW + (size_t)layer * kC * kC; shf = 7;
    base = wpack + (size_t)(layer * 288 + 0) * 512;
  } else if (r < 20480) {
    src = W1 + (size_t)layer * kC * kH; shf = 9;
    base = wpack + (size_t)(layer * 288 + 32) * 512; r -= 4096;
  } else {
    src = W2 + (size_t)layer * kH * kC; shf = 7;
    base = wpack + (size_t)(layer * 288 + 160) * 512; r -= 20480; isW2 = 1;
  }
  int e4 = r * 4;
  int k = e4 >> shf, n0 = e4 & ((1 << shf) - 1);
  float4 v = *(const float4*)(src + ((size_t)k << shf) + n0);
  float vv[4] = {v.x, v.y, v.z, v.w};
  int kb = k >> 5, hi = (k >> 3) & 3, j = k & 7;
#pragma unroll
  for (int t = 0; t < 4; ++t) {
    int n = n0 + t;
    int nb = n >> 4, l = hi * 16 + (n & 15);
    int f = isW2 ? (nb * 16 + kb) : (nb * 4 + kb);
    base[(size_t)f * 512 + l * 8 + j] = f2bf(vv[t]);
  }
}

// ---- fused GCN layer, channel-split: 2 blocks per graph, 64 output channels
// each. FIRST=true computes initial embeddings from coords on the fly.
// Residual read from the staged LDS tile (bf16) -- no second global read.
template <bool FIRST>
__global__ __launch_bounds__(256) void k_gcn(
    const float* __restrict__ yprev, const float* __restrict__ stats_prev,
    const float* __restrict__ gamma_p, const float* __restrict__ beta_p,
    const u16* __restrict__ Wg, const float* __restrict__ gb,
    float* __restrict__ stats_out, float* __restrict__ yA,
    const float* __restrict__ dxy, const float* __restrict__ cxy,
    const float* __restrict__ dem, const float* __restrict__ Wd,
    const float* __restrict__ bd, const float* __restrict__ Wi,
    const float* __restrict__ bi) {
  __shared__ float s_scale[kC], s_shift[kC];
  __shared__ u16 xs[112][136];       // 30.5 KB, rows >=100 are zero
  __shared__ float hs[kN][68];       // 27.2 KB
  __shared__ float sP[4][64], s_sum[64], s_sq[64];
  __shared__ float scoord[kN][4];    // FIRST only: (x, y, demand)
  __shared__ float swt[7][kC];       // FIRST only: Wd0,Wd1,bd,Wi0,Wi1,Wi2,bi
  const int tid = threadIdx.x;
  const int b = blockIdx.x >> 1, half = blockIdx.x & 1;
  const int wave = tid >> 6, lane = tid & 63;
  const int arow = lane & 15, kofs = (lane >> 4) * 8;
  const int crow = (lane >> 4) * 4, ccol = lane & 15;
  // issue B-frag loads EARLY (independent of LDS) so they fly under staging
  const int nbW = half * 4 + wave;
  bf16x8 bfr[4];
#pragma unroll
  for (int kb = 0; kb < 4; ++kb)
    bfr[kb] = *(const bf16x8*)(Wg + (size_t)(nbW * 4 + kb) * 512 + lane * 8);
  if (FIRST) {
    if (tid < kN) {
      if (tid == 0) {
        scoord[0][0] = dxy[b * 2];
        scoord[0][1] = dxy[b * 2 + 1];
        scoord[0][2] = 0.0f;
      } else {
        int q = b * kNC + tid - 1;
        scoord[tid][0] = cxy[q * 2];
        scoord[tid][1] = cxy[q * 2 + 1];
        scoord[tid][2] = dem[q];
      }
    }
    if (tid < 224) {
      int f = tid * 4, r = f >> 7, c = f & 127;
      const float* s;
      switch (r) {
        case 0: s = Wd + c; break;
        case 1: s = Wd + kC + c; break;
        case 2: s = bd + c; break;
        case 3: s = Wi + c; break;
        case 4: s = Wi + kC + c; break;
        case 5: s = Wi + 2 * kC + c; break;
        default: s = bi + c; break;
      }
      *(float4*)&swt[r][c] = *(const float4*)s;
    }
  }
  if (tid < kC) affine_from_stats(stats_prev, gamma_p, beta_p, tid,
                                  s_scale[tid], s_shift[tid]);
  if (tid < 64) { s_sum[tid] = 0.0f; s_sq[tid] = 0.0f; }
  __syncthreads();
  const size_t gbase = (size_t)b * kN * kC;
  // stage x (BN-affined, bf16) into LDS: 112*32 = 3584 float4-groups
#pragma unroll
  for (int i = 0; i < 14; ++i) {
    int li = i * 256 + tid;
    int lr = li >> 5, lc = (li & 31) * 4;
    float4 g = {0.f, 0.f, 0.f, 0.f};
    if (lr < kN) {
      if (FIRST) {
        float sx = scoord[lr][0], sy = scoord[lr][1], sd = scoord[lr][2];
        if (lr == 0) {
#pragma unroll
          for (int t = 0; t < 4; ++t)
            (&g.x)[t] = fmaf(sx, swt[0][lc + t],
                             fmaf(sy, swt[1][lc + t], swt[2][lc + t]));
        } else {
#pragma unroll
          for (int t = 0; t < 4; ++t)
            (&g.x)[t] = fmaf(sx, swt[3][lc + t],
                             fmaf(sy, swt[4][lc + t],
                                  fmaf(sd, swt[5][lc + t], swt[6][lc + t])));
        }
      } else {
        g = *(const float4*)(yprev + gbase + (size_t)lr * kC + lc);
      }
    }
    ushort4 h4;
    h4.x = f2bf(fmaf(g.x, s_scale[lc + 0], s_shift[lc + 0]));
    h4.y = f2bf(fmaf(g.y, s_scale[lc + 1], s_shift[lc + 1]));
    h4.z = f2bf(fmaf(g.z, s_scale[lc + 2], s_shift[lc + 2]));
    h4.w = f2bf(fmaf(g.w, s_scale[lc + 3], s_shift[lc + 3]));
    *(ushort4*)&xs[lr][lc] = h4;
  }
  __syncthreads();
  // wave w owns global col block nbW; MFMA over 7 row tiles
  {
#pragma unroll
    for (int t = 0; t < 7; ++t) {
      f32x4 acc = {0.f, 0.f, 0.f, 0.f};
#pragma unroll
      for (int kb = 0; kb < 4; ++kb) {
        bf16x8 a = *(const bf16x8*)&xs[t * 16 + arow][kb * 32 + kofs];
        acc = __builtin_amdgcn_mfma_f32_16x16x32_bf16(a, bfr[kb], acc, 0, 0, 0);
      }
      int rbase = t * 16 + crow;
#pragma unroll
      for (int r = 0; r < 4; ++r)
        if (rbase + r < kN) hs[rbase + r][wave * 16 + ccol] = acc[r];
    }
  }
  __syncthreads();
  // prefix over j (4-way split) for owned 64 channels; residual from xs (LDS)
  const int c = tid & 63, jh = tid >> 6;
  const int ch = half * 64 + c;
  const float gbc = gb[ch];
  const int j0 = jh * 25;
  float p = 0.0f;
#pragma unroll
  for (int jj = 0; jj < 25; ++jj)
    p = fmaf(hs[j0 + jj][c], rsqrtf((float)(j0 + jj + 1)), p);
  sP[jh][c] = p;
  __syncthreads();
  float s = 0.0f;
  for (int q = 0; q < jh; ++q) s += sP[q][c];
  float lsum = 0.0f, lsq = 0.0f;
#pragma unroll
  for (int jj = 0; jj < 25; ++jj) {
    int j = j0 + jj;
    float r = rsqrtf((float)(j + 1));
    s = fmaf(hs[j][c], r, s);
    float xv = bf2f(xs[j][ch]);          // staged affine(x), no global re-read
    float yv = xv + fmaf(s, r, gbc);
    yA[gbase + (size_t)j * kC + ch] = yv;
    lsum += yv;
    lsq = fmaf(yv, yv, lsq);
  }
  atomicAdd(&s_sum[c], lsum);
  atomicAdd(&s_sq[c], lsq);
  __syncthreads();
  if (tid < 64) {
    atomicAdd(&stats_out[half * 64 + tid], s_sum[tid]);
    atomicAdd(&stats_out[kC + half * 64 + tid], s_sq[tid]);
  }
}

// fused FF (MFMA bf16): 32-row tile, 8 waves. W2 frags preloaded at entry;
// residual read from staged LDS tile.
__global__ __launch_bounds__(512) void k_ff(
    const float* __restrict__ yA, const float* __restrict__ stats_in,
    const float* __restrict__ gamma, const float* __restrict__ beta,
    const u16* __restrict__ W1p, const float* __restrict__ b1,
    const u16* __restrict__ W2p, const float* __restrict__ b2,
    float* __restrict__ stats_out, float* __restrict__ yB) {
  __shared__ float s_scale[kC], s_shift[kC], s_sum[kC], s_sq[kC];
  __shared__ float s_b1[kH];
  __shared__ u16 xs[32][136];
  __shared__ u16 hid[32][520];
  const int tid = threadIdx.x;
  const int wave = tid >> 6, lane = tid & 63;
  const int arow = lane & 15, kofs = (lane >> 4) * 8;
  const int crow = (lane >> 4) * 4, ccol = lane & 15;
  // issue all 16 phase-2 W2 fragment loads NOW (T14 issue-early): they are
  // address-independent and their latency hides under staging + phase 1.
  const u16* w2f = W2p + lane * 8;
  bf16x8 bw[16];
#pragma unroll
  for (int kb = 0; kb < 16; ++kb)
    bw[kb] = *(const bf16x8*)(w2f + (size_t)(wave * 16 + kb) * 512);
  if (tid < kC) {
    affine_from_stats(stats_in, gamma, beta, tid, s_scale[tid], s_shift[tid]);
    s_sum[tid] = 0.0f;
    s_sq[tid] = 0.0f;
  }
  if (tid < 128) ((float4*)s_b1)[tid] = ((const float4*)b1)[tid];
  __syncthreads();
  const int rb = blockIdx.x * 32;
#pragma unroll
  for (int i = 0; i < 2; ++i) {
    int li = i * 2048 + tid * 4;
    int lr = li >> 7, lc = li & 127;
    float4 g = *(const float4*)(yA + (size_t)(rb + lr) * kC + lc);
    ushort4 h4;
    h4.x = f2bf(fmaf(g.x, s_scale[lc + 0], s_shift[lc + 0]));
    h4.y = f2bf(fmaf(g.y, s_scale[lc + 1], s_shift[lc + 1]));
    h4.z = f2bf(fmaf(g.z, s_scale[lc + 2], s_shift[lc + 2]));
    h4.w = f2bf(fmaf(g.w, s_scale[lc + 3], s_shift[lc + 3]));
    *(ushort4*)&xs[lr][lc] = h4;
  }
  __syncthreads();
  bf16x8 a[2][4];
#pragma unroll
  for (int rb2 = 0; rb2 < 2; ++rb2)
#pragma unroll
    for (int kb = 0; kb < 4; ++kb)
      a[rb2][kb] = *(const bf16x8*)&xs[rb2 * 16 + arow][kb * 32 + kofs];

  // ---- phase 1: hid = relu(xs @ W1 + b1); wave handles nb = wave*4 .. wave*4+3
  const u16* w1f = W1p + lane * 8;
#pragma unroll
  for (int t = 0; t < 4; ++t) {
    const int nb = wave * 4 + t;
    bf16x8 bfrag[4];
#pragma unroll
    for (int kb = 0; kb < 4; ++kb)
      bfrag[kb] = *(const bf16x8*)(w1f + (size_t)(nb * 4 + kb) * 512);
    f32x4 acc0 = {0.f, 0.f, 0.f, 0.f}, acc1 = {0.f, 0.f, 0.f, 0.f};
#pragma unroll
    for (int kb = 0; kb < 4; ++kb) {
      acc0 = __builtin_amdgcn_mfma_f32_16x16x32_bf16(a[0][kb], bfrag[kb], acc0, 0, 0, 0);
      acc1 = __builtin_amdgcn_mfma_f32_16x16x32_bf16(a[1][kb], bfrag[kb], acc1, 0, 0, 0);
    }
    const int c = nb * 16 + ccol;
    const float bbias = s_b1[c];
#pragma unroll
    for (int r = 0; r < 4; ++r) {
      hid[crow + r][c]      = f2bf(fmaxf(acc0[r] + bbias, 0.0f));
      hid[16 + crow + r][c] = f2bf(fmaxf(acc1[r] + bbias, 0.0f));
    }
  }
  __syncthreads();

  // ---- phase 2: out = x + hid @ W2 + b2; wave handles nb = wave (preloaded bw)
  f32x4 oacc0 = {0.f, 0.f, 0.f, 0.f}, oacc1 = {0.f, 0.f, 0.f, 0.f};
#pragma unroll
  for (int kb = 0; kb < 16; ++kb) {
    bf16x8 ha0 = *(const bf16x8*)&hid[arow][kb * 32 + kofs];
    bf16x8 ha1 = *(const bf16x8*)&hid[16 + arow][kb * 32 + kofs];
    oacc0 = __builtin_amdgcn_mfma_f32_16x16x32_bf16(ha0, bw[kb], oacc0, 0, 0, 0);
    oacc1 = __builtin_amdgcn_mfma_f32_16x16x32_bf16(ha1, bw[kb], oacc1, 0, 0, 0);
  }

  // ---- epilogue: bias + residual (from xs LDS), store, BN stats
  const int c = wave * 16 + ccol;
  const float bb = b2[c];
  float psum = 0.0f, psq = 0.0f;
#pragma unroll
  for (int rb2 = 0; rb2 < 2; ++rb2) {
#pragma unroll
    for (int r = 0; r < 4; ++r) {
      int lrow = rb2 * 16 + crow + r;
      float xv = bf2f(xs[lrow][c]);
      float o = (rb2 ? oacc1[r] : oacc0[r]) + bb + xv;
      yB[(size_t)(rb + lrow) * kC + c] = o;
      psum += o;
      psq = fmaf(o, o, psq);
    }
  }
  atomicAdd(&s_sum[c], psum);
  atomicAdd(&s_sq[c], psq);
  __syncthreads();
  if (tid < kC) {
    atomicAdd(&stats_out[tid], s_sum[tid]);
    atomicAdd(&stats_out[kC + tid], s_sq[tid]);
  }
}

// final BN apply + nodes out + per-graph mean, float4 vectorized, 16-way j-split
__global__ __launch_bounds__(512) void k_out(
    const float* __restrict__ yB, const float* __restrict__ stats,
    const float* __restrict__ gamma, const float* __restrict__ beta,
    float* __restrict__ out) {
  __shared__ float sP[16][kC];
  const int b = blockIdx.x;
  const int c4 = (threadIdx.x & 31) * 4, jh = threadIdx.x >> 5;  // 16 groups
  float sc[4], sh[4];
#pragma unroll
  for (int t = 0; t < 4; ++t)
    affine_from_stats(stats, gamma, beta, c4 + t, sc[t], sh[t]);
  const int j0 = (jh < 4) ? jh * 7 : 28 + (jh - 4) * 6;
  const int jc = (jh < 4) ? 7 : 6;
  const size_t base = (size_t)b * kN * kC;
  float acc[4] = {0.f, 0.f, 0.f, 0.f};
  for (int jj = 0; jj < jc; ++jj) {
    int j = j0 + jj;
    float4 g = *(const float4*)(yB + base + (size_t)j * kC + c4);
    float4 o;
    o.x = fmaf(g.x, sc[0], sh[0]);
    o.y = fmaf(g.y, sc[1], sh[1]);
    o.z = fmaf(g.z, sc[2], sh[2]);
    o.w = fmaf(g.w, sc[3], sh[3]);
    *(float4*)(out + base + (size_t)j * kC + c4) = o;
    acc[0] += o.x; acc[1] += o.y; acc[2] += o.z; acc[3] += o.w;
  }
#pragma unroll
  for (int t = 0; t < 4; ++t) sP[jh][c4 + t] = acc[t];
  __syncthreads();
  if (threadIdx.x < kC) {
    int c = threadIdx.x;
    float m = 0.0f;
#pragma unroll
    for (int q = 0; q < 16; ++q) m += sP[q][c];
    out[(size_t)kNT * kC + (size_t)b * kC + c] = m * (1.0f / kN);
  }
}

extern "C" void kernel_launch(void* const* d_in, const int* in_sizes, int n_in,
                              void* d_out, int out_size, void* d_ws, size_t ws_size,
                              hipStream_t stream) {
  const float* depot_xy    = (const float*)d_in[0];
  const float* customer_xy = (const float*)d_in[1];
  const float* demand      = (const float*)d_in[2];
  const float* W_depot     = (const float*)d_in[3];
  const float* b_depot     = (const float*)d_in[4];
  const float* W_init      = (const float*)d_in[5];
  const float* b_init      = (const float*)d_in[6];
  const float* gcn_W       = (const float*)d_in[7];
  const float* gcn_b       = (const float*)d_in[8];
  const float* bn_gamma    = (const float*)d_in[9];
  const float* bn_beta     = (const float*)d_in[10];
  const float* ff_W1       = (const float*)d_in[11];
  const float* ff_b1       = (const float*)d_in[12];
  const float* ff_W2       = (const float*)d_in[13];
  const float* ff_b2       = (const float*)d_in[14];

  float* ws    = (float*)d_ws;
  float* yA    = ws;
  float* yB    = ws + (size_t)kNT * kC;
  float* stats = ws + 2 * (size_t)kNT * kC;   // 6 slots x (sum[128], sumsq[128])
  u16*   wpack = (u16*)(stats + kL * 2 * 2 * kC);

  k_prep<<<432, 256, 0, stream>>>(gcn_W, ff_W1, ff_W2, wpack, stats);
  for (int l = 0; l < kL; ++l) {
    const float* sp = (l == 0) ? nullptr : stats + ((l - 1) * 2 + 1) * 2 * kC;
    const float* gp = (l == 0) ? nullptr : bn_gamma + (l - 1) * kC;
    const float* bp = (l == 0) ? nullptr : bn_beta + (l - 1) * kC;
    float* s0 = stats + (l * 2 + 0) * 2 * kC;
    float* s1 = stats + (l * 2 + 1) * 2 * kC;
    const u16* wg  = wpack + (size_t)(l * 288 + 0) * 512;
    const u16* w1p = wpack + (size_t)(l * 288 + 32) * 512;
    const u16* w2p = wpack + (size_t)(l * 288 + 160) * 512;
    if (l == 0) {
      k_gcn<true><<<kB * 2, 256, 0, stream>>>(
          nullptr, sp, gp, bp, wg, gcn_b + l * kC, s0, yA,
          depot_xy, customer_xy, demand, W_depot, b_depot, W_init, b_init);
    } else {
      k_gcn<false><<<kB * 2, 256, 0, stream>>>(
          yB, sp, gp, bp, wg, gcn_b + l * kC, s0, yA,
          nullptr, nullptr, nullptr, nullptr, nullptr, nullptr, nullptr);
    }
    k_ff<<<kNT / 32, 512, 0, stream>>>(yA, s0, bn_gamma + l * kC, bn_beta + l * kC,
                                       w1p, ff_b1 + l * kH,
                                       w2p, ff_b2 + l * kC,
                                       s1, yB);
  }
  k_out<<<kB, 512, 0, stream>>>(yB, stats + (2 * 2 + 1) * 2 * kC,
                                bn_gamma + 2 * kC, bn_beta + 2 * kC, (float*)d_out);
}

// Round 9
// 164.905 us; speedup vs baseline: 1.0104x; 1.0104x over previous
//
#include <hip/hip_runtime.h>

constexpr int kB = 256;
constexpr int kNC = 99;
constexpr int kN = 100;
constexpr int kC = 128;
constexpr int kH = 512;
constexpr int kL = 3;
constexpr int kNT = kB * kN;   // 25600
constexpr float kEps = 1e-5f;

typedef unsigned short u16;
typedef unsigned int u32;
typedef __attribute__((ext_vector_type(8))) __bf16 bf16x8;
typedef __attribute__((ext_vector_type(4))) float f32x4;

__device__ __forceinline__ u16 f2bf(float x) {
  __bf16 h = (__bf16)x;                 // native v_cvt (RNE), 1 VALU op
  return __builtin_bit_cast(u16, h);
}
__device__ __forceinline__ float bf2f(u16 h) {
  union { u32 u; float f; } v; v.u = ((u32)h) << 16;
  return v.f;
}

// per-channel BN affine from raw (sum, sumsq) stats; stats==nullptr -> identity
__device__ __forceinline__ void affine_from_stats(
    const float* __restrict__ stats, const float* __restrict__ gamma,
    const float* __restrict__ beta, int c, float& sc, float& sh) {
  if (stats != nullptr) {
    float s = stats[c], sq = stats[kC + c];
    float m = s * (1.0f / kNT);
    float v = sq * (1.0f / kNT) - m * m;
    float rs = rsqrtf(v + kEps);
    sc = gamma[c] * rs;
    sh = beta[c] - m * sc;
  } else {
    sc = 1.0f;
    sh = 0.0f;
  }
}

// ---- weight pack (432 blocks) + stats zero.
__global__ __launch_bounds__(256) void k_prep(
    const float* __restrict__ gcnW, const float* __restrict__ W1,
    const float* __restrict__ W2, u16* __restrict__ wpack,
    float* __restrict__ stats) {
  if (blockIdx.x == 0) {
    for (int i = threadIdx.x; i < kL * 2 * 2 * kC; i += 256) stats[i] = 0.0f;
  }
  int g = blockIdx.x * 256 + threadIdx.x;          // < 110592 float4-groups
  int layer = g / 36864, r = g % 36864;
  const float* src; int shf; u16* base; int isW2 = 0;
  if (r < 4096) {
    src = gcnW + (size_t)layer * kC * kC; shf = 7;
    base = wpack + (size_t)(layer * 288 + 0) * 512;
  } else if (r < 20480) {
    src = W1 + (size_t)layer * kC * kH; shf = 9;
    base = wpack + (size_t)(layer * 288 + 32) * 512; r -= 4096;
  } else {
    src = W2 + (size_t)layer * kH * kC; shf = 7;
    base = wpack + (size_t)(layer * 288 + 160) * 512; r -= 20480; isW2 = 1;
  }
  int e4 = r * 4;
  int k = e4 >> shf, n0 = e4 & ((1 << shf) - 1);
  float4 v = *(const float4*)(src + ((size_t)k << shf) + n0);
  float vv[4] = {v.x, v.y, v.z, v.w};
  int kb = k >> 5, hi = (k >> 3) & 3, j = k & 7;
#pragma unroll
  for (int t = 0; t < 4; ++t) {
    int n = n0 + t;
    int nb = n >> 4, l = hi * 16 + (n & 15);
    int f = isW2 ? (nb * 16 + kb) : (nb * 4 + kb);
    base[(size_t)f * 512 + l * 8 + j] = f2bf(vv[t]);
  }
}

// ---- fused GCN layer, channel-split: 2 blocks per graph, 64 output channels
// each, 512 threads (8 waves). MFMA row-halves split across wave pairs;
// prefix j-split 8 ways. Residual from staged LDS tile (bf16).
template <bool FIRST>
__global__ __launch_bounds__(512) void k_gcn(
    const float* __restrict__ yprev, const float* __restrict__ stats_prev,
    const float* __restrict__ gamma_p, const float* __restrict__ beta_p,
    const u16* __restrict__ Wg, const float* __restrict__ gb,
    float* __restrict__ stats_out, float* __restrict__ yA,
    const float* __restrict__ dxy, const float* __restrict__ cxy,
    const float* __restrict__ dem, const float* __restrict__ Wd,
    const float* __restrict__ bd, const float* __restrict__ Wi,
    const float* __restrict__ bi) {
  __shared__ float s_scale[kC], s_shift[kC];
  __shared__ u16 xs[112][136];       // 30.5 KB, rows >=100 are zero
  __shared__ float hs[kN][68];       // 27.2 KB
  __shared__ float sP[8][64], s_sum[64], s_sq[64];
  __shared__ float scoord[kN][4];    // FIRST only
  __shared__ float swt[7][kC];       // FIRST only
  const int tid = threadIdx.x;
  const int b = blockIdx.x >> 1, half = blockIdx.x & 1;
  const int wave = tid >> 6, lane = tid & 63;
  const int arow = lane & 15, kofs = (lane >> 4) * 8;
  const int crow = (lane >> 4) * 4, ccol = lane & 15;
  // wave -> (col-block, row-half)
  const int nbl = wave & 3;                 // local col block 0..3
  const int nbW = half * 4 + nbl;           // global col block
  const int th = wave >> 2;                 // row half
  // issue B-frag loads EARLY so they fly under staging
  bf16x8 bfr[4];
#pragma unroll
  for (int kb = 0; kb < 4; ++kb)
    bfr[kb] = *(const bf16x8*)(Wg + (size_t)(nbW * 4 + kb) * 512 + lane * 8);
  if (FIRST) {
    if (tid < kN) {
      if (tid == 0) {
        scoord[0][0] = dxy[b * 2];
        scoord[0][1] = dxy[b * 2 + 1];
        scoord[0][2] = 0.0f;
      } else {
        int q = b * kNC + tid - 1;
        scoord[tid][0] = cxy[q * 2];
        scoord[tid][1] = cxy[q * 2 + 1];
        scoord[tid][2] = dem[q];
      }
    } else if (tid >= 256 && tid < 480) {
      int f = (tid - 256) * 4, r = f >> 7, c = f & 127;
      const float* s;
      switch (r) {
        case 0: s = Wd + c; break;
        case 1: s = Wd + kC + c; break;
        case 2: s = bd + c; break;
        case 3: s = Wi + c; break;
        case 4: s = Wi + kC + c; break;
        case 5: s = Wi + 2 * kC + c; break;
        default: s = bi + c; break;
      }
      *(float4*)&swt[r][c] = *(const float4*)s;
    }
  }
  if (tid >= 128 && tid < 256)
    affine_from_stats(stats_prev, gamma_p, beta_p, tid - 128,
                      s_scale[tid - 128], s_shift[tid - 128]);
  if (tid < 64) { s_sum[tid] = 0.0f; s_sq[tid] = 0.0f; }
  __syncthreads();
  const size_t gbase = (size_t)b * kN * kC;
  // stage x (BN-affined, bf16) into LDS: 3584 float4-groups, 7 iters
#pragma unroll
  for (int i = 0; i < 7; ++i) {
    int li = i * 512 + tid;
    int lr = li >> 5, lc = (li & 31) * 4;
    float4 g = {0.f, 0.f, 0.f, 0.f};
    if (lr < kN) {
      if (FIRST) {
        float sx = scoord[lr][0], sy = scoord[lr][1], sd = scoord[lr][2];
        if (lr == 0) {
#pragma unroll
          for (int t = 0; t < 4; ++t)
            (&g.x)[t] = fmaf(sx, swt[0][lc + t],
                             fmaf(sy, swt[1][lc + t], swt[2][lc + t]));
        } else {
#pragma unroll
          for (int t = 0; t < 4; ++t)
            (&g.x)[t] = fmaf(sx, swt[3][lc + t],
                             fmaf(sy, swt[4][lc + t],
                                  fmaf(sd, swt[5][lc + t], swt[6][lc + t])));
        }
      } else {
        g = *(const float4*)(yprev + gbase + (size_t)lr * kC + lc);
      }
    }
    ushort4 h4;
    h4.x = f2bf(fmaf(g.x, s_scale[lc + 0], s_shift[lc + 0]));
    h4.y = f2bf(fmaf(g.y, s_scale[lc + 1], s_shift[lc + 1]));
    h4.z = f2bf(fmaf(g.z, s_scale[lc + 2], s_shift[lc + 2]));
    h4.w = f2bf(fmaf(g.w, s_scale[lc + 3], s_shift[lc + 3]));
    *(ushort4*)&xs[lr][lc] = h4;
  }
  __syncthreads();
  // MFMA: wave handles col block nbl, row tiles th*4 .. (th?6:3)
  {
    const int t0 = th * 4, t1 = th ? 7 : 4;
    for (int t = t0; t < t1; ++t) {
      f32x4 acc = {0.f, 0.f, 0.f, 0.f};
#pragma unroll
      for (int kb = 0; kb < 4; ++kb) {
        bf16x8 a = *(const bf16x8*)&xs[t * 16 + arow][kb * 32 + kofs];
        acc = __builtin_amdgcn_mfma_f32_16x16x32_bf16(a, bfr[kb], acc, 0, 0, 0);
      }
      int rbase = t * 16 + crow;
#pragma unroll
      for (int r = 0; r < 4; ++r)
        if (rbase + r < kN) hs[rbase + r][nbl * 16 + ccol] = acc[r];
    }
  }
  __syncthreads();
  // prefix over j (8-way split) for owned 64 channels; residual from xs (LDS)
  const int c = tid & 63, jh = tid >> 6;
  const int ch = half * 64 + c;
  const float gbc = gb[ch];
  const int j0 = (jh < 4) ? jh * 13 : 52 + (jh - 4) * 12;
  const int jcnt = (jh < 4) ? 13 : 12;
  float p = 0.0f;
  for (int jj = 0; jj < jcnt; ++jj) {
    int j = j0 + jj;
    p = fmaf(hs[j][c], rsqrtf((float)(j + 1)), p);
  }
  sP[jh][c] = p;
  __syncthreads();
  float s = 0.0f;
  for (int q = 0; q < jh; ++q) s += sP[q][c];
  float lsum = 0.0f, lsq = 0.0f;
  for (int jj = 0; jj < jcnt; ++jj) {
    int j = j0 + jj;
    float r = rsqrtf((float)(j + 1));
    s = fmaf(hs[j][c], r, s);
    float xv = bf2f(xs[j][ch]);          // staged affine(x), no global re-read
    float yv = xv + fmaf(s, r, gbc);
    yA[gbase + (size_t)j * kC + ch] = yv;
    lsum += yv;
    lsq = fmaf(yv, yv, lsq);
  }
  atomicAdd(&s_sum[c], lsum);
  atomicAdd(&s_sq[c], lsq);
  __syncthreads();
  if (tid < 64) {
    atomicAdd(&stats_out[half * 64 + tid], s_sum[tid]);
    atomicAdd(&stats_out[kC + half * 64 + tid], s_sq[tid]);
  }
}

// fused FF (MFMA bf16): 32-row tile, 8 waves. On-demand W2 loads (round-7
// codegen, VGPR-friendly); residual read from staged LDS tile.
__global__ __launch_bounds__(512) void k_ff(
    const float* __restrict__ yA, const float* __restrict__ stats_in,
    const float* __restrict__ gamma, const float* __restrict__ beta,
    const u16* __restrict__ W1p, const float* __restrict__ b1,
    const u16* __restrict__ W2p, const float* __restrict__ b2,
    float* __restrict__ stats_out, float* __restrict__ yB) {
  __shared__ float s_scale[kC], s_shift[kC], s_sum[kC], s_sq[kC];
  __shared__ float s_b1[kH];
  __shared__ u16 xs[32][136];
  __shared__ u16 hid[32][520];
  const int tid = threadIdx.x;
  const int wave = tid >> 6, lane = tid & 63;
  const int arow = lane & 15, kofs = (lane >> 4) * 8;
  const int crow = (lane >> 4) * 4, ccol = lane & 15;
  if (tid < kC) {
    affine_from_stats(stats_in, gamma, beta, tid, s_scale[tid], s_shift[tid]);
    s_sum[tid] = 0.0f;
    s_sq[tid] = 0.0f;
  }
  if (tid < 128) ((float4*)s_b1)[tid] = ((const float4*)b1)[tid];
  __syncthreads();
  const int rb = blockIdx.x * 32;
#pragma unroll
  for (int i = 0; i < 2; ++i) {
    int li = i * 2048 + tid * 4;
    int lr = li >> 7, lc = li & 127;
    float4 g = *(const float4*)(yA + (size_t)(rb + lr) * kC + lc);
    ushort4 h4;
    h4.x = f2bf(fmaf(g.x, s_scale[lc + 0], s_shift[lc + 0]));
    h4.y = f2bf(fmaf(g.y, s_scale[lc + 1], s_shift[lc + 1]));
    h4.z = f2bf(fmaf(g.z, s_scale[lc + 2], s_shift[lc + 2]));
    h4.w = f2bf(fmaf(g.w, s_scale[lc + 3], s_shift[lc + 3]));
    *(ushort4*)&xs[lr][lc] = h4;
  }
  __syncthreads();
  bf16x8 a[2][4];
#pragma unroll
  for (int rb2 = 0; rb2 < 2; ++rb2)
#pragma unroll
    for (int kb = 0; kb < 4; ++kb)
      a[rb2][kb] = *(const bf16x8*)&xs[rb2 * 16 + arow][kb * 32 + kofs];

  // ---- phase 1: hid = relu(xs @ W1 + b1); wave handles nb = wave*4 .. wave*4+3
  const u16* w1f = W1p + lane * 8;
#pragma unroll
  for (int t = 0; t < 4; ++t) {
    const int nb = wave * 4 + t;
    bf16x8 bfrag[4];
#pragma unroll
    for (int kb = 0; kb < 4; ++kb)
      bfrag[kb] = *(const bf16x8*)(w1f + (size_t)(nb * 4 + kb) * 512);
    f32x4 acc0 = {0.f, 0.f, 0.f, 0.f}, acc1 = {0.f, 0.f, 0.f, 0.f};
#pragma unroll
    for (int kb = 0; kb < 4; ++kb) {
      acc0 = __builtin_amdgcn_mfma_f32_16x16x32_bf16(a[0][kb], bfrag[kb], acc0, 0, 0, 0);
      acc1 = __builtin_amdgcn_mfma_f32_16x16x32_bf16(a[1][kb], bfrag[kb], acc1, 0, 0, 0);
    }
    const int c = nb * 16 + ccol;
    const float bbias = s_b1[c];
#pragma unroll
    for (int r = 0; r < 4; ++r) {
      hid[crow + r][c]      = f2bf(fmaxf(acc0[r] + bbias, 0.0f));
      hid[16 + crow + r][c] = f2bf(fmaxf(acc1[r] + bbias, 0.0f));
    }
  }
  __syncthreads();

  // ---- phase 2: out = x + hid @ W2 + b2; wave handles nb = wave
  const u16* w2f = W2p + lane * 8;
  f32x4 oacc0 = {0.f, 0.f, 0.f, 0.f}, oacc1 = {0.f, 0.f, 0.f, 0.f};
#pragma unroll
  for (int kb = 0; kb < 16; ++kb) {
    bf16x8 bfrag = *(const bf16x8*)(w2f + (size_t)(wave * 16 + kb) * 512);
    bf16x8 ha0 = *(const bf16x8*)&hid[arow][kb * 32 + kofs];
    bf16x8 ha1 = *(const bf16x8*)&hid[16 + arow][kb * 32 + kofs];
    oacc0 = __builtin_amdgcn_mfma_f32_16x16x32_bf16(ha0, bfrag, oacc0, 0, 0, 0);
    oacc1 = __builtin_amdgcn_mfma_f32_16x16x32_bf16(ha1, bfrag, oacc1, 0, 0, 0);
  }

  // ---- epilogue: bias + residual (from xs LDS), store, BN stats
  const int c = wave * 16 + ccol;
  const float bb = b2[c];
  float psum = 0.0f, psq = 0.0f;
#pragma unroll
  for (int rb2 = 0; rb2 < 2; ++rb2) {
#pragma unroll
    for (int r = 0; r < 4; ++r) {
      int lrow = rb2 * 16 + crow + r;
      float xv = bf2f(xs[lrow][c]);
      float o = (rb2 ? oacc1[r] : oacc0[r]) + bb + xv;
      yB[(size_t)(rb + lrow) * kC + c] = o;
      psum += o;
      psq = fmaf(o, o, psq);
    }
  }
  atomicAdd(&s_sum[c], psum);
  atomicAdd(&s_sq[c], psq);
  __syncthreads();
  if (tid < kC) {
    atomicAdd(&stats_out[tid], s_sum[tid]);
    atomicAdd(&stats_out[kC + tid], s_sq[tid]);
  }
}

// final BN apply + nodes out + per-graph mean, float4 vectorized, 16-way j-split
__global__ __launch_bounds__(512) void k_out(
    const float* __restrict__ yB, const float* __restrict__ stats,
    const float* __restrict__ gamma, const float* __restrict__ beta,
    float* __restrict__ out) {
  __shared__ float sP[16][kC];
  const int b = blockIdx.x;
  const int c4 = (threadIdx.x & 31) * 4, jh = threadIdx.x >> 5;  // 16 groups
  float sc[4], sh[4];
#pragma unroll
  for (int t = 0; t < 4; ++t)
    affine_from_stats(stats, gamma, beta, c4 + t, sc[t], sh[t]);
  const int j0 = (jh < 4) ? jh * 7 : 28 + (jh - 4) * 6;
  const int jc = (jh < 4) ? 7 : 6;
  const size_t base = (size_t)b * kN * kC;
  float acc[4] = {0.f, 0.f, 0.f, 0.f};
  for (int jj = 0; jj < jc; ++jj) {
    int j = j0 + jj;
    float4 g = *(const float4*)(yB + base + (size_t)j * kC + c4);
    float4 o;
    o.x = fmaf(g.x, sc[0], sh[0]);
    o.y = fmaf(g.y, sc[1], sh[1]);
    o.z = fmaf(g.z, sc[2], sh[2]);
    o.w = fmaf(g.w, sc[3], sh[3]);
    *(float4*)(out + base + (size_t)j * kC + c4) = o;
    acc[0] += o.x; acc[1] += o.y; acc[2] += o.z; acc[3] += o.w;
  }
#pragma unroll
  for (int t = 0; t < 4; ++t) sP[jh][c4 + t] = acc[t];
  __syncthreads();
  if (threadIdx.x < kC) {
    int c = threadIdx.x;
    float m = 0.0f;
#pragma unroll
    for (int q = 0; q < 16; ++q) m += sP[q][c];
    out[(size_t)kNT * kC + (size_t)b * kC + c] = m * (1.0f / kN);
  }
}

extern "C" void kernel_launch(void* const* d_in, const int* in_sizes, int n_in,
                              void* d_out, int out_size, void* d_ws, size_t ws_size,
                              hipStream_t stream) {
  const float* depot_xy    = (const float*)d_in[0];
  const float* customer_xy = (const float*)d_in[1];
  const float* demand      = (const float*)d_in[2];
  const float* W_depot     = (const float*)d_in[3];
  const float* b_depot     = (const float*)d_in[4];
  const float* W_init      = (const float*)d_in[5];
  const float* b_init      = (const float*)d_in[6];
  const float* gcn_W       = (const float*)d_in[7];
  const float* gcn_b       = (const float*)d_in[8];
  const float* bn_gamma    = (const float*)d_in[9];
  const float* bn_beta     = (const float*)d_in[10];
  const float* ff_W1       = (const float*)d_in[11];
  const float* ff_b1       = (const float*)d_in[12];
  const float* ff_W2       = (const float*)d_in[13];
  const float* ff_b2       = (const float*)d_in[14];

  float* ws    = (float*)d_ws;
  float* yA    = ws;
  float* yB    = ws + (size_t)kNT * kC;
  float* stats = ws + 2 * (size_t)kNT * kC;   // 6 slots x (sum[128], sumsq[128])
  u16*   wpack = (u16*)(stats + kL * 2 * 2 * kC);

  k_prep<<<432, 256, 0, stream>>>(gcn_W, ff_W1, ff_W2, wpack, stats);
  for (int l = 0; l < kL; ++l) {
    const float* sp = (l == 0) ? nullptr : stats + ((l - 1) * 2 + 1) * 2 * kC;
    const float* gp = (l == 0) ? nullptr : bn_gamma + (l - 1) * kC;
    const float* bp = (l == 0) ? nullptr : bn_beta + (l - 1) * kC;
    float* s0 = stats + (l * 2 + 0) * 2 * kC;
    float* s1 = stats + (l * 2 + 1) * 2 * kC;
    const u16* wg  = wpack + (size_t)(l * 288 + 0) * 512;
    const u16* w1p = wpack + (size_t)(l * 288 + 32) * 512;
    const u16* w2p = wpack + (size_t)(l * 288 + 160) * 512;
    if (l == 0) {
      k_gcn<true><<<kB * 2, 512, 0, stream>>>(
          nullptr, sp, gp, bp, wg, gcn_b + l * kC, s0, yA,
          depot_xy, customer_xy, demand, W_depot, b_depot, W_init, b_init);
    } else {
      k_gcn<false><<<kB * 2, 512, 0, stream>>>(
          yB, sp, gp, bp, wg, gcn_b + l * kC, s0, yA,
          nullptr, nullptr, nullptr, nullptr, nullptr, nullptr, nullptr);
    }
    k_ff<<<kNT / 32, 512, 0, stream>>>(yA, s0, bn_gamma + l * kC, bn_beta + l * kC,
                                       w1p, ff_b1 + l * kH,
                                       w2p, ff_b2 + l * kC,
                                       s1, yB);
  }
  k_out<<<kB, 512, 0, stream>>>(yB, stats + (2 * 2 + 1) * 2 * kC,
                                bn_gamma + 2 * kC, bn_beta + 2 * kC, (float*)d_out);
}

// Round 10
// 154.542 us; speedup vs baseline: 1.0782x; 1.0671x over previous
//
#include <hip/hip_runtime.h>

constexpr int kB = 256;
constexpr int kNC = 99;
constexpr int kN = 100;
constexpr int kC = 128;
constexpr int kH = 512;
constexpr int kL = 3;
constexpr int kNT = kB * kN;   // 25600
constexpr float kEps = 1e-5f;

typedef unsigned short u16;
typedef unsigned int u32;
typedef __attribute__((ext_vector_type(8))) __bf16 bf16x8;
typedef __attribute__((ext_vector_type(4))) float f32x4;
typedef __attribute__((ext_vector_type(8))) unsigned short u16x8;

__device__ __forceinline__ u16 f2bf(float x) {
  __bf16 h = (__bf16)x;                 // native v_cvt (RNE)
  return __builtin_bit_cast(u16, h);
}
__device__ __forceinline__ float bf2f(u16 h) {
  union { u32 u; float f; } v; v.u = ((u32)h) << 16;
  return v.f;
}

// per-channel BN affine from raw (sum, sumsq) stats; stats==nullptr -> identity
__device__ __forceinline__ void affine_from_stats(
    const float* __restrict__ stats, const float* __restrict__ gamma,
    const float* __restrict__ beta, int c, float& sc, float& sh) {
  if (stats != nullptr) {
    float s = stats[c], sq = stats[kC + c];
    float m = s * (1.0f / kNT);
    float v = sq * (1.0f / kNT) - m * m;
    float rs = rsqrtf(v + kEps);
    sc = gamma[c] * rs;
    sh = beta[c] - m * sc;
  } else {
    sc = 1.0f;
    sh = 0.0f;
  }
}

// ---- weight pack (432 blocks) + stats zero.
__global__ __launch_bounds__(256) void k_prep(
    const float* __restrict__ gcnW, const float* __restrict__ W1,
    const float* __restrict__ W2, u16* __restrict__ wpack,
    float* __restrict__ stats) {
  if (blockIdx.x == 0) {
    for (int i = threadIdx.x; i < kL * 2 * 2 * kC; i += 256) stats[i] = 0.0f;
  }
  int g = blockIdx.x * 256 + threadIdx.x;          // < 110592 float4-groups
  int layer = g / 36864, r = g % 36864;
  const float* src; int shf; u16* base; int isW2 = 0;
  if (r < 4096) {
    src = gcnW + (size_t)layer * kC * kC; shf = 7;
    base = wpack + (size_t)(layer * 288 + 0) * 512;
  } else if (r < 20480) {
    src = W1 + (size_t)layer * kC * kH; shf = 9;
    base = wpack + (size_t)(layer * 288 + 32) * 512; r -= 4096;
  } else {
    src = W2 + (size_t)layer * kH * kC; shf = 7;
    base = wpack + (size_t)(layer * 288 + 160) * 512; r -= 20480; isW2 = 1;
  }
  int e4 = r * 4;
  int k = e4 >> shf, n0 = e4 & ((1 << shf) - 1);
  float4 v = *(const float4*)(src + ((size_t)k << shf) + n0);
  float vv[4] = {v.x, v.y, v.z, v.w};
  int kb = k >> 5, hi = (k >> 3) & 3, j = k & 7;
#pragma unroll
  for (int t = 0; t < 4; ++t) {
    int n = n0 + t;
    int nb = n >> 4, l = hi * 16 + (n & 15);
    int f = isW2 ? (nb * 16 + kb) : (nb * 4 + kb);
    base[(size_t)f * 512 + l * 8 + j] = f2bf(vv[t]);
  }
}

// ---- fused GCN layer, channel-split: 2 blocks per graph, 64 output channels
// each, 256 threads (4 waves). bf16 activation I/O. FIRST computes initial
// embeddings from coords. Residual re-read from global bf16 (single rounding).
template <bool FIRST>
__global__ __launch_bounds__(256) void k_gcn(
    const u16* __restrict__ yprev, const float* __restrict__ stats_prev,
    const float* __restrict__ gamma_p, const float* __restrict__ beta_p,
    const u16* __restrict__ Wg, const float* __restrict__ gb,
    float* __restrict__ stats_out, u16* __restrict__ yA,
    const float* __restrict__ dxy, const float* __restrict__ cxy,
    const float* __restrict__ dem, const float* __restrict__ Wd,
    const float* __restrict__ bd, const float* __restrict__ Wi,
    const float* __restrict__ bi) {
  __shared__ float s_scale[kC], s_shift[kC];
  __shared__ u16 xs[112][136];       // 30.5 KB, rows >=100 are zero
  __shared__ float hs[kN][68];       // 27.2 KB
  __shared__ float sP[4][64], s_sum[64], s_sq[64];
  __shared__ float scoord[kN][4];    // FIRST only
  __shared__ float swt[7][kC];       // FIRST only
  const int tid = threadIdx.x;
  const int b = blockIdx.x >> 1, half = blockIdx.x & 1;
  const int wave = tid >> 6, lane = tid & 63;
  const int arow = lane & 15, kofs = (lane >> 4) * 8;
  const int crow = (lane >> 4) * 4, ccol = lane & 15;
  // issue B-frag loads EARLY so they fly under staging
  const int nbW = half * 4 + wave;
  bf16x8 bfr[4];
#pragma unroll
  for (int kb = 0; kb < 4; ++kb)
    bfr[kb] = *(const bf16x8*)(Wg + (size_t)(nbW * 4 + kb) * 512 + lane * 8);
  if (FIRST) {
    if (tid < kN) {
      if (tid == 0) {
        scoord[0][0] = dxy[b * 2];
        scoord[0][1] = dxy[b * 2 + 1];
        scoord[0][2] = 0.0f;
      } else {
        int q = b * kNC + tid - 1;
        scoord[tid][0] = cxy[q * 2];
        scoord[tid][1] = cxy[q * 2 + 1];
        scoord[tid][2] = dem[q];
      }
    }
    if (tid < 224) {
      int f = tid * 4, r = f >> 7, c = f & 127;
      const float* s;
      switch (r) {
        case 0: s = Wd + c; break;
        case 1: s = Wd + kC + c; break;
        case 2: s = bd + c; break;
        case 3: s = Wi + c; break;
        case 4: s = Wi + kC + c; break;
        case 5: s = Wi + 2 * kC + c; break;
        default: s = bi + c; break;
      }
      *(float4*)&swt[r][c] = *(const float4*)s;
    }
  }
  if (tid < kC) affine_from_stats(stats_prev, gamma_p, beta_p, tid,
                                  s_scale[tid], s_shift[tid]);
  if (tid < 64) { s_sum[tid] = 0.0f; s_sq[tid] = 0.0f; }
  __syncthreads();
  const size_t gbase = (size_t)b * kN * kC;
  // stage x (BN-affined, bf16) into LDS: 3584 4-channel groups, 14 iters
#pragma unroll
  for (int i = 0; i < 14; ++i) {
    int li = i * 256 + tid;
    int lr = li >> 5, lc = (li & 31) * 4;
    float g0 = 0.f, g1 = 0.f, g2 = 0.f, g3 = 0.f;
    if (lr < kN) {
      if (FIRST) {
        float sx = scoord[lr][0], sy = scoord[lr][1], sd = scoord[lr][2];
        if (lr == 0) {
          g0 = fmaf(sx, swt[0][lc + 0], fmaf(sy, swt[1][lc + 0], swt[2][lc + 0]));
          g1 = fmaf(sx, swt[0][lc + 1], fmaf(sy, swt[1][lc + 1], swt[2][lc + 1]));
          g2 = fmaf(sx, swt[0][lc + 2], fmaf(sy, swt[1][lc + 2], swt[2][lc + 2]));
          g3 = fmaf(sx, swt[0][lc + 3], fmaf(sy, swt[1][lc + 3], swt[2][lc + 3]));
        } else {
          g0 = fmaf(sx, swt[3][lc + 0],
                    fmaf(sy, swt[4][lc + 0], fmaf(sd, swt[5][lc + 0], swt[6][lc + 0])));
          g1 = fmaf(sx, swt[3][lc + 1],
                    fmaf(sy, swt[4][lc + 1], fmaf(sd, swt[5][lc + 1], swt[6][lc + 1])));
          g2 = fmaf(sx, swt[3][lc + 2],
                    fmaf(sy, swt[4][lc + 2], fmaf(sd, swt[5][lc + 2], swt[6][lc + 2])));
          g3 = fmaf(sx, swt[3][lc + 3],
                    fmaf(sy, swt[4][lc + 3], fmaf(sd, swt[5][lc + 3], swt[6][lc + 3])));
        }
      } else {
        ushort4 hv = *(const ushort4*)(yprev + gbase + (size_t)lr * kC + lc);
        g0 = bf2f(hv.x); g1 = bf2f(hv.y); g2 = bf2f(hv.z); g3 = bf2f(hv.w);
      }
    }
    ushort4 h4;
    h4.x = f2bf(fmaf(g0, s_scale[lc + 0], s_shift[lc + 0]));
    h4.y = f2bf(fmaf(g1, s_scale[lc + 1], s_shift[lc + 1]));
    h4.z = f2bf(fmaf(g2, s_scale[lc + 2], s_shift[lc + 2]));
    h4.w = f2bf(fmaf(g3, s_scale[lc + 3], s_shift[lc + 3]));
    *(ushort4*)&xs[lr][lc] = h4;
  }
  __syncthreads();
  // MFMA: wave w owns global col block nbW over all 7 row tiles
  {
#pragma unroll
    for (int t = 0; t < 7; ++t) {
      f32x4 acc = {0.f, 0.f, 0.f, 0.f};
#pragma unroll
      for (int kb = 0; kb < 4; ++kb) {
        bf16x8 a = *(const bf16x8*)&xs[t * 16 + arow][kb * 32 + kofs];
        acc = __builtin_amdgcn_mfma_f32_16x16x32_bf16(a, bfr[kb], acc, 0, 0, 0);
      }
      int rbase = t * 16 + crow;
#pragma unroll
      for (int r = 0; r < 4; ++r)
        if (rbase + r < kN) hs[rbase + r][wave * 16 + ccol] = acc[r];
    }
  }
  __syncthreads();
  // prefix over j (4-way split) for owned 64 channels; residual from global bf16
  const int c = tid & 63, jh = tid >> 6;
  const int ch = half * 64 + c;
  const float sc = s_scale[ch], sh = s_shift[ch];
  const float gbc = gb[ch];
  const int j0 = jh * 25;
  float p = 0.0f;
#pragma unroll
  for (int jj = 0; jj < 25; ++jj)
    p = fmaf(hs[j0 + jj][c], rsqrtf((float)(j0 + jj + 1)), p);
  sP[jh][c] = p;
  __syncthreads();
  float s = 0.0f;
  for (int q = 0; q < jh; ++q) s += sP[q][c];
  float wv0 = 0.f, wv1 = 0.f, wv2 = 0.f, wv3 = 0.f, wd0 = 0.f, wd1 = 0.f, wd2 = 0.f;
  if (FIRST) {
    wv0 = swt[3][ch]; wv1 = swt[4][ch]; wv2 = swt[5][ch]; wv3 = swt[6][ch];
    wd0 = swt[0][ch]; wd1 = swt[1][ch]; wd2 = swt[2][ch];
  }
  float lsum = 0.0f, lsq = 0.0f;
#pragma unroll
  for (int jj = 0; jj < 25; ++jj) {
    int j = j0 + jj;
    float r = rsqrtf((float)(j + 1));
    s = fmaf(hs[j][c], r, s);
    float xv;
    if (FIRST) {
      float sx = scoord[j][0], sy = scoord[j][1], sd = scoord[j][2];
      xv = (j == 0) ? fmaf(sx, wd0, fmaf(sy, wd1, wd2))
                    : fmaf(sx, wv0, fmaf(sy, wv1, fmaf(sd, wv2, wv3)));
    } else {
      xv = fmaf(bf2f(yprev[gbase + (size_t)j * kC + ch]), sc, sh);
    }
    float yv = xv + fmaf(s, r, gbc);
    yA[gbase + (size_t)j * kC + ch] = f2bf(yv);
    lsum += yv;
    lsq = fmaf(yv, yv, lsq);
  }
  atomicAdd(&s_sum[c], lsum);
  atomicAdd(&s_sq[c], lsq);
  __syncthreads();
  if (tid < 64) {
    atomicAdd(&stats_out[half * 64 + tid], s_sum[tid]);
    atomicAdd(&stats_out[kC + half * 64 + tid], s_sq[tid]);
  }
}

// fused FF (MFMA bf16): 32-row tile, 8 waves, bf16 input; LAST writes f32.
// Residual re-read from global bf16.
template <bool LAST>
__global__ __launch_bounds__(512) void k_ff(
    const u16* __restrict__ yA, const float* __restrict__ stats_in,
    const float* __restrict__ gamma, const float* __restrict__ beta,
    const u16* __restrict__ W1p, const float* __restrict__ b1,
    const u16* __restrict__ W2p, const float* __restrict__ b2,
    float* __restrict__ stats_out, u16* __restrict__ yB16,
    float* __restrict__ yB32) {
  __shared__ float s_scale[kC], s_shift[kC], s_sum[kC], s_sq[kC];
  __shared__ float s_b1[kH];
  __shared__ u16 xs[32][136];
  __shared__ u16 hid[32][520];
  const int tid = threadIdx.x;
  const int wave = tid >> 6, lane = tid & 63;
  const int arow = lane & 15, kofs = (lane >> 4) * 8;
  const int crow = (lane >> 4) * 4, ccol = lane & 15;
  if (tid < kC) {
    affine_from_stats(stats_in, gamma, beta, tid, s_scale[tid], s_shift[tid]);
    s_sum[tid] = 0.0f;
    s_sq[tid] = 0.0f;
  }
  if (tid < 128) ((float4*)s_b1)[tid] = ((const float4*)b1)[tid];
  __syncthreads();
  const int rb = blockIdx.x * 32;
  // stage: 512 8-channel groups, exactly one per thread (ushort8 = 16B load)
  {
    int lr = tid >> 4, lc8 = (tid & 15) * 8;
    u16x8 hv = *(const u16x8*)(yA + (size_t)(rb + lr) * kC + lc8);
    u16x8 o;
#pragma unroll
    for (int e = 0; e < 8; ++e)
      o[e] = f2bf(fmaf(bf2f(hv[e]), s_scale[lc8 + e], s_shift[lc8 + e]));
    *(u16x8*)&xs[lr][lc8] = o;
  }
  __syncthreads();
  bf16x8 a[2][4];
#pragma unroll
  for (int rb2 = 0; rb2 < 2; ++rb2)
#pragma unroll
    for (int kb = 0; kb < 4; ++kb)
      a[rb2][kb] = *(const bf16x8*)&xs[rb2 * 16 + arow][kb * 32 + kofs];

  // ---- phase 1: hid = relu(xs @ W1 + b1); wave handles nb = wave*4 .. wave*4+3
  const u16* w1f = W1p + lane * 8;
#pragma unroll
  for (int t = 0; t < 4; ++t) {
    const int nb = wave * 4 + t;
    bf16x8 bfrag[4];
#pragma unroll
    for (int kb = 0; kb < 4; ++kb)
      bfrag[kb] = *(const bf16x8*)(w1f + (size_t)(nb * 4 + kb) * 512);
    f32x4 acc0 = {0.f, 0.f, 0.f, 0.f}, acc1 = {0.f, 0.f, 0.f, 0.f};
#pragma unroll
    for (int kb = 0; kb < 4; ++kb) {
      acc0 = __builtin_amdgcn_mfma_f32_16x16x32_bf16(a[0][kb], bfrag[kb], acc0, 0, 0, 0);
      acc1 = __builtin_amdgcn_mfma_f32_16x16x32_bf16(a[1][kb], bfrag[kb], acc1, 0, 0, 0);
    }
    const int c = nb * 16 + ccol;
    const float bbias = s_b1[c];
#pragma unroll
    for (int r = 0; r < 4; ++r) {
      hid[crow + r][c]      = f2bf(fmaxf(acc0[r] + bbias, 0.0f));
      hid[16 + crow + r][c] = f2bf(fmaxf(acc1[r] + bbias, 0.0f));
    }
  }
  __syncthreads();

  // ---- phase 2: out = x + hid @ W2 + b2; wave handles nb = wave
  const u16* w2f = W2p + lane * 8;
  f32x4 oacc0 = {0.f, 0.f, 0.f, 0.f}, oacc1 = {0.f, 0.f, 0.f, 0.f};
#pragma unroll
  for (int kb = 0; kb < 16; ++kb) {
    bf16x8 bfrag = *(const bf16x8*)(w2f + (size_t)(wave * 16 + kb) * 512);
    bf16x8 ha0 = *(const bf16x8*)&hid[arow][kb * 32 + kofs];
    bf16x8 ha1 = *(const bf16x8*)&hid[16 + arow][kb * 32 + kofs];
    oacc0 = __builtin_amdgcn_mfma_f32_16x16x32_bf16(ha0, bfrag, oacc0, 0, 0, 0);
    oacc1 = __builtin_amdgcn_mfma_f32_16x16x32_bf16(ha1, bfrag, oacc1, 0, 0, 0);
  }

  // ---- epilogue: bias + residual (global bf16 re-read), store, BN stats
  const int c = wave * 16 + ccol;
  const float sc = s_scale[c], sh = s_shift[c], bb = b2[c];
  float psum = 0.0f, psq = 0.0f;
#pragma unroll
  for (int rb2 = 0; rb2 < 2; ++rb2) {
#pragma unroll
    for (int r = 0; r < 4; ++r) {
      int lrow = rb2 * 16 + crow + r;
      float xv = fmaf(bf2f(yA[(size_t)(rb + lrow) * kC + c]), sc, sh);
      float o = (rb2 ? oacc1[r] : oacc0[r]) + bb + xv;
      if (LAST)
        yB32[(size_t)(rb + lrow) * kC + c] = o;
      else
        yB16[(size_t)(rb + lrow) * kC + c] = f2bf(o);
      psum += o;
      psq = fmaf(o, o, psq);
    }
  }
  atomicAdd(&s_sum[c], psum);
  atomicAdd(&s_sq[c], psq);
  __syncthreads();
  if (tid < kC) {
    atomicAdd(&stats_out[tid], s_sum[tid]);
    atomicAdd(&stats_out[kC + tid], s_sq[tid]);
  }
}

// final BN apply + nodes out + per-graph mean, 4-way j-split (f32 input)
__global__ __launch_bounds__(512) void k_out(
    const float* __restrict__ yB, const float* __restrict__ stats,
    const float* __restrict__ gamma, const float* __restrict__ beta,
    float* __restrict__ out) {
  __shared__ float sP[4][kC];
  const int b = blockIdx.x;
  const int c = threadIdx.x & 127, jh = threadIdx.x >> 7;
  float sc, sh;
  affine_from_stats(stats, gamma, beta, c, sc, sh);
  float acc = 0.0f;
  const size_t base = (size_t)b * kN * kC + c;
  const int j0 = jh * 25;
#pragma unroll
  for (int jj = 0; jj < 25; ++jj) {
    float xv = fmaf(yB[base + (size_t)(j0 + jj) * kC], sc, sh);
    out[base + (size_t)(j0 + jj) * kC] = xv;
    acc += xv;
  }
  sP[jh][c] = acc;
  __syncthreads();
  if (jh == 0)
    out[(size_t)kNT * kC + (size_t)b * kC + c] =
        (sP[0][c] + sP[1][c] + sP[2][c] + sP[3][c]) * (1.0f / kN);
}

extern "C" void kernel_launch(void* const* d_in, const int* in_sizes, int n_in,
                              void* d_out, int out_size, void* d_ws, size_t ws_size,
                              hipStream_t stream) {
  const float* depot_xy    = (const float*)d_in[0];
  const float* customer_xy = (const float*)d_in[1];
  const float* demand      = (const float*)d_in[2];
  const float* W_depot     = (const float*)d_in[3];
  const float* b_depot     = (const float*)d_in[4];
  const float* W_init      = (const float*)d_in[5];
  const float* b_init      = (const float*)d_in[6];
  const float* gcn_W       = (const float*)d_in[7];
  const float* gcn_b       = (const float*)d_in[8];
  const float* bn_gamma    = (const float*)d_in[9];
  const float* bn_beta     = (const float*)d_in[10];
  const float* ff_W1       = (const float*)d_in[11];
  const float* ff_b1       = (const float*)d_in[12];
  const float* ff_W2       = (const float*)d_in[13];
  const float* ff_b2       = (const float*)d_in[14];

  u16*   yA16  = (u16*)d_ws;                       // NT*kC bf16
  u16*   yB16  = yA16 + (size_t)kNT * kC;          // NT*kC bf16
  float* yB32  = (float*)(yB16 + (size_t)kNT * kC);// NT*kC f32 (last layer)
  float* stats = yB32 + (size_t)kNT * kC;          // 6 x (sum[128], sumsq[128])
  u16*   wpack = (u16*)(stats + kL * 2 * 2 * kC);

  k_prep<<<432, 256, 0, stream>>>(gcn_W, ff_W1, ff_W2, wpack, stats);
  for (int l = 0; l < kL; ++l) {
    const float* sp = (l == 0) ? nullptr : stats + ((l - 1) * 2 + 1) * 2 * kC;
    const float* gp = (l == 0) ? nullptr : bn_gamma + (l - 1) * kC;
    const float* bp = (l == 0) ? nullptr : bn_beta + (l - 1) * kC;
    float* s0 = stats + (l * 2 + 0) * 2 * kC;
    float* s1 = stats + (l * 2 + 1) * 2 * kC;
    const u16* wg  = wpack + (size_t)(l * 288 + 0) * 512;
    const u16* w1p = wpack + (size_t)(l * 288 + 32) * 512;
    const u16* w2p = wpack + (size_t)(l * 288 + 160) * 512;
    if (l == 0) {
      k_gcn<true><<<kB * 2, 256, 0, stream>>>(
          nullptr, sp, gp, bp, wg, gcn_b + l * kC, s0, yA16,
          depot_xy, customer_xy, demand, W_depot, b_depot, W_init, b_init);
    } else {
      k_gcn<false><<<kB * 2, 256, 0, stream>>>(
          yB16, sp, gp, bp, wg, gcn_b + l * kC, s0, yA16,
          nullptr, nullptr, nullptr, nullptr, nullptr, nullptr, nullptr);
    }
    if (l < kL - 1) {
      k_ff<false><<<kNT / 32, 512, 0, stream>>>(
          yA16, s0, bn_gamma + l * kC, bn_beta + l * kC,
          w1p, ff_b1 + l * kH, w2p, ff_b2 + l * kC, s1, yB16, nullptr);
    } else {
      k_ff<true><<<kNT / 32, 512, 0, stream>>>(
          yA16, s0, bn_gamma + l * kC, bn_beta + l * kC,
          w1p, ff_b1 + l * kH, w2p, ff_b2 + l * kC, s1, nullptr, yB32);
    }
  }
  k_out<<<kB, 512, 0, stream>>>(yB32, stats + (2 * 2 + 1) * 2 * kC,
                                bn_gamma + 2 * kC, bn_beta + 2 * kC, (float*)d_out);
}

// Round 11
// 151.992 us; speedup vs baseline: 1.0963x; 1.0168x over previous
//
#include <hip/hip_runtime.h>

constexpr int kB = 256;
constexpr int kNC = 99;
constexpr int kN = 100;
constexpr int kC = 128;
constexpr int kH = 512;
constexpr int kL = 3;
constexpr int kNT = kB * kN;   // 25600
constexpr int kRT = 48;        // k_ff rows per block (3 x 16-row MFMA tiles)
constexpr int kFFBlocks = (kNT + kRT - 1) / kRT;   // 534
constexpr float kEps = 1e-5f;

typedef unsigned short u16;
typedef unsigned int u32;
typedef __attribute__((ext_vector_type(8))) __bf16 bf16x8;
typedef __attribute__((ext_vector_type(4))) float f32x4;
typedef __attribute__((ext_vector_type(8))) unsigned short u16x8;

__device__ __forceinline__ u16 f2bf(float x) {
  __bf16 h = (__bf16)x;                 // native v_cvt (RNE)
  return __builtin_bit_cast(u16, h);
}
__device__ __forceinline__ float bf2f(u16 h) {
  union { u32 u; float f; } v; v.u = ((u32)h) << 16;
  return v.f;
}

// per-channel BN affine from raw (sum, sumsq) stats; stats==nullptr -> identity
__device__ __forceinline__ void affine_from_stats(
    const float* __restrict__ stats, const float* __restrict__ gamma,
    const float* __restrict__ beta, int c, float& sc, float& sh) {
  if (stats != nullptr) {
    float s = stats[c], sq = stats[kC + c];
    float m = s * (1.0f / kNT);
    float v = sq * (1.0f / kNT) - m * m;
    float rs = rsqrtf(v + kEps);
    sc = gamma[c] * rs;
    sh = beta[c] - m * sc;
  } else {
    sc = 1.0f;
    sh = 0.0f;
  }
}

// ---- weight pack (432 blocks) + stats zero.
__global__ __launch_bounds__(256) void k_prep(
    const float* __restrict__ gcnW, const float* __restrict__ W1,
    const float* __restrict__ W2, u16* __restrict__ wpack,
    float* __restrict__ stats) {
  if (blockIdx.x == 0) {
    for (int i = threadIdx.x; i < kL * 2 * 2 * kC; i += 256) stats[i] = 0.0f;
  }
  int g = blockIdx.x * 256 + threadIdx.x;          // < 110592 float4-groups
  int layer = g / 36864, r = g % 36864;
  const float* src; int shf; u16* base; int isW2 = 0;
  if (r < 4096) {
    src = gcnW + (size_t)layer * kC * kC; shf = 7;
    base = wpack + (size_t)(layer * 288 + 0) * 512;
  } else if (r < 20480) {
    src = W1 + (size_t)layer * kC * kH; shf = 9;
    base = wpack + (size_t)(layer * 288 + 32) * 512; r -= 4096;
  } else {
    src = W2 + (size_t)layer * kH * kC; shf = 7;
    base = wpack + (size_t)(layer * 288 + 160) * 512; r -= 20480; isW2 = 1;
  }
  int e4 = r * 4;
  int k = e4 >> shf, n0 = e4 & ((1 << shf) - 1);
  float4 v = *(const float4*)(src + ((size_t)k << shf) + n0);
  float vv[4] = {v.x, v.y, v.z, v.w};
  int kb = k >> 5, hi = (k >> 3) & 3, j = k & 7;
#pragma unroll
  for (int t = 0; t < 4; ++t) {
    int n = n0 + t;
    int nb = n >> 4, l = hi * 16 + (n & 15);
    int f = isW2 ? (nb * 16 + kb) : (nb * 4 + kb);
    base[(size_t)f * 512 + l * 8 + j] = f2bf(vv[t]);
  }
}

// ---- fused GCN layer, channel-split: 2 blocks per graph, 64 output channels
// each, 256 threads (4 waves). bf16 activation I/O. FIRST computes initial
// embeddings from coords. Residual re-read from global bf16 (single rounding).
template <bool FIRST>
__global__ __launch_bounds__(256) void k_gcn(
    const u16* __restrict__ yprev, const float* __restrict__ stats_prev,
    const float* __restrict__ gamma_p, const float* __restrict__ beta_p,
    const u16* __restrict__ Wg, const float* __restrict__ gb,
    float* __restrict__ stats_out, u16* __restrict__ yA,
    const float* __restrict__ dxy, const float* __restrict__ cxy,
    const float* __restrict__ dem, const float* __restrict__ Wd,
    const float* __restrict__ bd, const float* __restrict__ Wi,
    const float* __restrict__ bi) {
  __shared__ float s_scale[kC], s_shift[kC];
  __shared__ u16 xs[112][136];       // 30.5 KB, rows >=100 are zero
  __shared__ float hs[kN][68];       // 27.2 KB
  __shared__ float sP[4][64], s_sum[64], s_sq[64];
  __shared__ float scoord[kN][4];    // FIRST only
  __shared__ float swt[7][kC];       // FIRST only
  const int tid = threadIdx.x;
  const int b = blockIdx.x >> 1, half = blockIdx.x & 1;
  const int wave = tid >> 6, lane = tid & 63;
  const int arow = lane & 15, kofs = (lane >> 4) * 8;
  const int crow = (lane >> 4) * 4, ccol = lane & 15;
  // issue B-frag loads EARLY so they fly under staging
  const int nbW = half * 4 + wave;
  bf16x8 bfr[4];
#pragma unroll
  for (int kb = 0; kb < 4; ++kb)
    bfr[kb] = *(const bf16x8*)(Wg + (size_t)(nbW * 4 + kb) * 512 + lane * 8);
  if (FIRST) {
    if (tid < kN) {
      if (tid == 0) {
        scoord[0][0] = dxy[b * 2];
        scoord[0][1] = dxy[b * 2 + 1];
        scoord[0][2] = 0.0f;
      } else {
        int q = b * kNC + tid - 1;
        scoord[tid][0] = cxy[q * 2];
        scoord[tid][1] = cxy[q * 2 + 1];
        scoord[tid][2] = dem[q];
      }
    }
    if (tid < 224) {
      int f = tid * 4, r = f >> 7, c = f & 127;
      const float* s;
      switch (r) {
        case 0: s = Wd + c; break;
        case 1: s = Wd + kC + c; break;
        case 2: s = bd + c; break;
        case 3: s = Wi + c; break;
        case 4: s = Wi + kC + c; break;
        case 5: s = Wi + 2 * kC + c; break;
        default: s = bi + c; break;
      }
      *(float4*)&swt[r][c] = *(const float4*)s;
    }
  }
  if (tid < kC) affine_from_stats(stats_prev, gamma_p, beta_p, tid,
                                  s_scale[tid], s_shift[tid]);
  if (tid < 64) { s_sum[tid] = 0.0f; s_sq[tid] = 0.0f; }
  __syncthreads();
  const size_t gbase = (size_t)b * kN * kC;
  // stage x (BN-affined, bf16) into LDS: 3584 4-channel groups, 14 iters
#pragma unroll
  for (int i = 0; i < 14; ++i) {
    int li = i * 256 + tid;
    int lr = li >> 5, lc = (li & 31) * 4;
    float g0 = 0.f, g1 = 0.f, g2 = 0.f, g3 = 0.f;
    if (lr < kN) {
      if (FIRST) {
        float sx = scoord[lr][0], sy = scoord[lr][1], sd = scoord[lr][2];
        if (lr == 0) {
          g0 = fmaf(sx, swt[0][lc + 0], fmaf(sy, swt[1][lc + 0], swt[2][lc + 0]));
          g1 = fmaf(sx, swt[0][lc + 1], fmaf(sy, swt[1][lc + 1], swt[2][lc + 1]));
          g2 = fmaf(sx, swt[0][lc + 2], fmaf(sy, swt[1][lc + 2], swt[2][lc + 2]));
          g3 = fmaf(sx, swt[0][lc + 3], fmaf(sy, swt[1][lc + 3], swt[2][lc + 3]));
        } else {
          g0 = fmaf(sx, swt[3][lc + 0],
                    fmaf(sy, swt[4][lc + 0], fmaf(sd, swt[5][lc + 0], swt[6][lc + 0])));
          g1 = fmaf(sx, swt[3][lc + 1],
                    fmaf(sy, swt[4][lc + 1], fmaf(sd, swt[5][lc + 1], swt[6][lc + 1])));
          g2 = fmaf(sx, swt[3][lc + 2],
                    fmaf(sy, swt[4][lc + 2], fmaf(sd, swt[5][lc + 2], swt[6][lc + 2])));
          g3 = fmaf(sx, swt[3][lc + 3],
                    fmaf(sy, swt[4][lc + 3], fmaf(sd, swt[5][lc + 3], swt[6][lc + 3])));
        }
      } else {
        ushort4 hv = *(const ushort4*)(yprev + gbase + (size_t)lr * kC + lc);
        g0 = bf2f(hv.x); g1 = bf2f(hv.y); g2 = bf2f(hv.z); g3 = bf2f(hv.w);
      }
    }
    ushort4 h4;
    h4.x = f2bf(fmaf(g0, s_scale[lc + 0], s_shift[lc + 0]));
    h4.y = f2bf(fmaf(g1, s_scale[lc + 1], s_shift[lc + 1]));
    h4.z = f2bf(fmaf(g2, s_scale[lc + 2], s_shift[lc + 2]));
    h4.w = f2bf(fmaf(g3, s_scale[lc + 3], s_shift[lc + 3]));
    *(ushort4*)&xs[lr][lc] = h4;
  }
  __syncthreads();
  // MFMA: wave w owns global col block nbW over all 7 row tiles
  {
#pragma unroll
    for (int t = 0; t < 7; ++t) {
      f32x4 acc = {0.f, 0.f, 0.f, 0.f};
#pragma unroll
      for (int kb = 0; kb < 4; ++kb) {
        bf16x8 a = *(const bf16x8*)&xs[t * 16 + arow][kb * 32 + kofs];
        acc = __builtin_amdgcn_mfma_f32_16x16x32_bf16(a, bfr[kb], acc, 0, 0, 0);
      }
      int rbase = t * 16 + crow;
#pragma unroll
      for (int r = 0; r < 4; ++r)
        if (rbase + r < kN) hs[rbase + r][wave * 16 + ccol] = acc[r];
    }
  }
  __syncthreads();
  // prefix over j (4-way split) for owned 64 channels; residual from global bf16
  const int c = tid & 63, jh = tid >> 6;
  const int ch = half * 64 + c;
  const float sc = s_scale[ch], sh = s_shift[ch];
  const float gbc = gb[ch];
  const int j0 = jh * 25;
  float p = 0.0f;
#pragma unroll
  for (int jj = 0; jj < 25; ++jj)
    p = fmaf(hs[j0 + jj][c], rsqrtf((float)(j0 + jj + 1)), p);
  sP[jh][c] = p;
  __syncthreads();
  float s = 0.0f;
  for (int q = 0; q < jh; ++q) s += sP[q][c];
  float wv0 = 0.f, wv1 = 0.f, wv2 = 0.f, wv3 = 0.f, wd0 = 0.f, wd1 = 0.f, wd2 = 0.f;
  if (FIRST) {
    wv0 = swt[3][ch]; wv1 = swt[4][ch]; wv2 = swt[5][ch]; wv3 = swt[6][ch];
    wd0 = swt[0][ch]; wd1 = swt[1][ch]; wd2 = swt[2][ch];
  }
  float lsum = 0.0f, lsq = 0.0f;
#pragma unroll
  for (int jj = 0; jj < 25; ++jj) {
    int j = j0 + jj;
    float r = rsqrtf((float)(j + 1));
    s = fmaf(hs[j][c], r, s);
    float xv;
    if (FIRST) {
      float sx = scoord[j][0], sy = scoord[j][1], sd = scoord[j][2];
      xv = (j == 0) ? fmaf(sx, wd0, fmaf(sy, wd1, wd2))
                    : fmaf(sx, wv0, fmaf(sy, wv1, fmaf(sd, wv2, wv3)));
    } else {
      xv = fmaf(bf2f(yprev[gbase + (size_t)j * kC + ch]), sc, sh);
    }
    float yv = xv + fmaf(s, r, gbc);
    yA[gbase + (size_t)j * kC + ch] = f2bf(yv);
    lsum += yv;
    lsq = fmaf(yv, yv, lsq);
  }
  atomicAdd(&s_sum[c], lsum);
  atomicAdd(&s_sq[c], lsq);
  __syncthreads();
  if (tid < 64) {
    atomicAdd(&stats_out[half * 64 + tid], s_sum[tid]);
    atomicAdd(&stats_out[kC + half * 64 + tid], s_sq[tid]);
  }
}

// fused FF (MFMA bf16): 48-row tile (3 x 16-row MFMA tiles), 534 blocks,
// 8 waves. One resident scheduling round at 2 blocks/CU. bf16 activation I/O;
// LAST writes f32. Residual loads issued before phase 2 (latency hidden).
template <bool LAST>
__global__ __launch_bounds__(512) void k_ff(
    const u16* __restrict__ yA, const float* __restrict__ stats_in,
    const float* __restrict__ gamma, const float* __restrict__ beta,
    const u16* __restrict__ W1p, const float* __restrict__ b1,
    const u16* __restrict__ W2p, const float* __restrict__ b2,
    float* __restrict__ stats_out, u16* __restrict__ yB16,
    float* __restrict__ yB32) {
  __shared__ float s_scale[kC], s_shift[kC], s_sum[kC], s_sq[kC];
  __shared__ float s_b1[kH];
  __shared__ u16 xs[kRT][136];       // 13.1 KB
  __shared__ u16 hid[kRT][520];      // 49.9 KB
  const int tid = threadIdx.x;
  const int wave = tid >> 6, lane = tid & 63;
  const int arow = lane & 15, kofs = (lane >> 4) * 8;
  const int crow = (lane >> 4) * 4, ccol = lane & 15;
  if (tid < kC) {
    affine_from_stats(stats_in, gamma, beta, tid, s_scale[tid], s_shift[tid]);
    s_sum[tid] = 0.0f;
    s_sq[tid] = 0.0f;
  }
  if (tid < 128) ((float4*)s_b1)[tid] = ((const float4*)b1)[tid];
  __syncthreads();
  const int rb = blockIdx.x * kRT;
  const int nvalid = (kNT - rb < kRT) ? (kNT - rb) : kRT;   // 48, tail 16
  // stage: 768 8-channel groups (ushort8 = 16B loads), zero pad invalid rows
#pragma unroll
  for (int i = 0; i < 2; ++i) {
    int li = i * 512 + tid;
    if (li < kRT * 16) {
      int lr = li >> 4, lc8 = (li & 15) * 8;
      u16x8 o = {0, 0, 0, 0, 0, 0, 0, 0};
      if (lr < nvalid) {
        u16x8 hv = *(const u16x8*)(yA + (size_t)(rb + lr) * kC + lc8);
#pragma unroll
        for (int e = 0; e < 8; ++e)
          o[e] = f2bf(fmaf(bf2f(hv[e]), s_scale[lc8 + e], s_shift[lc8 + e]));
      }
      *(u16x8*)&xs[lr][lc8] = o;
    }
  }
  __syncthreads();
  bf16x8 a[3][4];
#pragma unroll
  for (int rt = 0; rt < 3; ++rt)
#pragma unroll
    for (int kb = 0; kb < 4; ++kb)
      a[rt][kb] = *(const bf16x8*)&xs[rt * 16 + arow][kb * 32 + kofs];

  // ---- phase 1: hid = relu(xs @ W1 + b1); wave handles nb = wave*4 .. wave*4+3
  const u16* w1f = W1p + lane * 8;
#pragma unroll
  for (int t = 0; t < 4; ++t) {
    const int nb = wave * 4 + t;
    bf16x8 bfrag[4];
#pragma unroll
    for (int kb = 0; kb < 4; ++kb)
      bfrag[kb] = *(const bf16x8*)(w1f + (size_t)(nb * 4 + kb) * 512);
    f32x4 acc[3] = {{0.f, 0.f, 0.f, 0.f}, {0.f, 0.f, 0.f, 0.f}, {0.f, 0.f, 0.f, 0.f}};
#pragma unroll
    for (int kb = 0; kb < 4; ++kb) {
#pragma unroll
      for (int rt = 0; rt < 3; ++rt)
        acc[rt] = __builtin_amdgcn_mfma_f32_16x16x32_bf16(a[rt][kb], bfrag[kb], acc[rt], 0, 0, 0);
    }
    const int c = nb * 16 + ccol;
    const float bbias = s_b1[c];
#pragma unroll
    for (int rt = 0; rt < 3; ++rt)
#pragma unroll
      for (int r = 0; r < 4; ++r)
        hid[rt * 16 + crow + r][c] = f2bf(fmaxf(acc[rt][r] + bbias, 0.0f));
  }
  __syncthreads();

  // residual loads issued BEFORE phase 2 so L2 latency hides under MFMA
  const int c = wave * 16 + ccol;
  u16 resid[12];
#pragma unroll
  for (int rt = 0; rt < 3; ++rt)
#pragma unroll
    for (int r = 0; r < 4; ++r) {
      int lrow = rt * 16 + crow + r;
      resid[rt * 4 + r] = (lrow < nvalid) ? yA[(size_t)(rb + lrow) * kC + c] : (u16)0;
    }

  // ---- phase 2: out = x + hid @ W2 + b2; wave handles nb = wave
  const u16* w2f = W2p + lane * 8;
  f32x4 oacc[3] = {{0.f, 0.f, 0.f, 0.f}, {0.f, 0.f, 0.f, 0.f}, {0.f, 0.f, 0.f, 0.f}};
#pragma unroll
  for (int kb = 0; kb < 16; ++kb) {
    bf16x8 bfrag = *(const bf16x8*)(w2f + (size_t)(wave * 16 + kb) * 512);
#pragma unroll
    for (int rt = 0; rt < 3; ++rt) {
      bf16x8 ha = *(const bf16x8*)&hid[rt * 16 + arow][kb * 32 + kofs];
      oacc[rt] = __builtin_amdgcn_mfma_f32_16x16x32_bf16(ha, bfrag, oacc[rt], 0, 0, 0);
    }
  }

  // ---- epilogue: bias + residual, store, BN stats (valid rows only)
  const float sc = s_scale[c], sh = s_shift[c], bb = b2[c];
  float psum = 0.0f, psq = 0.0f;
#pragma unroll
  for (int rt = 0; rt < 3; ++rt) {
#pragma unroll
    for (int r = 0; r < 4; ++r) {
      int lrow = rt * 16 + crow + r;
      if (lrow < nvalid) {
        float xv = fmaf(bf2f(resid[rt * 4 + r]), sc, sh);
        float o = oacc[rt][r] + bb + xv;
        if (LAST)
          yB32[(size_t)(rb + lrow) * kC + c] = o;
        else
          yB16[(size_t)(rb + lrow) * kC + c] = f2bf(o);
        psum += o;
        psq = fmaf(o, o, psq);
      }
    }
  }
  atomicAdd(&s_sum[c], psum);
  atomicAdd(&s_sq[c], psq);
  __syncthreads();
  if (tid < kC) {
    atomicAdd(&stats_out[tid], s_sum[tid]);
    atomicAdd(&stats_out[kC + tid], s_sq[tid]);
  }
}

// final BN apply + nodes out + per-graph mean, 4-way j-split (f32 input)
__global__ __launch_bounds__(512) void k_out(
    const float* __restrict__ yB, const float* __restrict__ stats,
    const float* __restrict__ gamma, const float* __restrict__ beta,
    float* __restrict__ out) {
  __shared__ float sP[4][kC];
  const int b = blockIdx.x;
  const int c = threadIdx.x & 127, jh = threadIdx.x >> 7;
  float sc, sh;
  affine_from_stats(stats, gamma, beta, c, sc, sh);
  float acc = 0.0f;
  const size_t base = (size_t)b * kN * kC + c;
  const int j0 = jh * 25;
#pragma unroll
  for (int jj = 0; jj < 25; ++jj) {
    float xv = fmaf(yB[base + (size_t)(j0 + jj) * kC], sc, sh);
    out[base + (size_t)(j0 + jj) * kC] = xv;
    acc += xv;
  }
  sP[jh][c] = acc;
  __syncthreads();
  if (jh == 0)
    out[(size_t)kNT * kC + (size_t)b * kC + c] =
        (sP[0][c] + sP[1][c] + sP[2][c] + sP[3][c]) * (1.0f / kN);
}

extern "C" void kernel_launch(void* const* d_in, const int* in_sizes, int n_in,
                              void* d_out, int out_size, void* d_ws, size_t ws_size,
                              hipStream_t stream) {
  const float* depot_xy    = (const float*)d_in[0];
  const float* customer_xy = (const float*)d_in[1];
  const float* demand      = (const float*)d_in[2];
  const float* W_depot     = (const float*)d_in[3];
  const float* b_depot     = (const float*)d_in[4];
  const float* W_init      = (const float*)d_in[5];
  const float* b_init      = (const float*)d_in[6];
  const float* gcn_W       = (const float*)d_in[7];
  const float* gcn_b       = (const float*)d_in[8];
  const float* bn_gamma    = (const float*)d_in[9];
  const float* bn_beta     = (const float*)d_in[10];
  const float* ff_W1       = (const float*)d_in[11];
  const float* ff_b1       = (const float*)d_in[12];
  const float* ff_W2       = (const float*)d_in[13];
  const float* ff_b2       = (const float*)d_in[14];

  u16*   yA16  = (u16*)d_ws;                       // NT*kC bf16
  u16*   yB16  = yA16 + (size_t)kNT * kC;          // NT*kC bf16
  float* yB32  = (float*)(yB16 + (size_t)kNT * kC);// NT*kC f32 (last layer)
  float* stats = yB32 + (size_t)kNT * kC;          // 6 x (sum[128], sumsq[128])
  u16*   wpack = (u16*)(stats + kL * 2 * 2 * kC);

  k_prep<<<432, 256, 0, stream>>>(gcn_W, ff_W1, ff_W2, wpack, stats);
  for (int l = 0; l < kL; ++l) {
    const float* sp = (l == 0) ? nullptr : stats + ((l - 1) * 2 + 1) * 2 * kC;
    const float* gp = (l == 0) ? nullptr : bn_gamma + (l - 1) * kC;
    const float* bp = (l == 0) ? nullptr : bn_beta + (l - 1) * kC;
    float* s0 = stats + (l * 2 + 0) * 2 * kC;
    float* s1 = stats + (l * 2 + 1) * 2 * kC;
    const u16* wg  = wpack + (size_t)(l * 288 + 0) * 512;
    const u16* w1p = wpack + (size_t)(l * 288 + 32) * 512;
    const u16* w2p = wpack + (size_t)(l * 288 + 160) * 512;
    if (l == 0) {
      k_gcn<true><<<kB * 2, 256, 0, stream>>>(
          nullptr, sp, gp, bp, wg, gcn_b + l * kC, s0, yA16,
          depot_xy, customer_xy, demand, W_depot, b_depot, W_init, b_init);
    } else {
      k_gcn<false><<<kB * 2, 256, 0, stream>>>(
          yB16, sp, gp, bp, wg, gcn_b + l * kC, s0, yA16,
          nullptr, nullptr, nullptr, nullptr, nullptr, nullptr, nullptr);
    }
    if (l < kL - 1) {
      k_ff<false><<<kFFBlocks, 512, 0, stream>>>(
          yA16, s0, bn_gamma + l * kC, bn_beta + l * kC,
          w1p, ff_b1 + l * kH, w2p, ff_b2 + l * kC, s1, yB16, nullptr);
    } else {
      k_ff<true><<<kFFBlocks, 512, 0, stream>>>(
          yA16, s0, bn_gamma + l * kC, bn_beta + l * kC,
          w1p, ff_b1 + l * kH, w2p, ff_b2 + l * kC, s1, nullptr, yB32);
    }
  }
  k_out<<<kB, 512, 0, stream>>>(yB32, stats + (2 * 2 + 1) * 2 * kC,
                                bn_gamma + 2 * kC, bn_beta + 2 * kC, (float*)d_out);
}

// Round 12
// 129.366 us; speedup vs baseline: 1.2880x; 1.1749x over previous
//
#include <hip/hip_runtime.h>

constexpr int kB = 256;
constexpr int kNC = 99;
constexpr int kN = 100;
constexpr int kC = 128;
constexpr int kH = 512;
constexpr int kL = 3;
constexpr int kNT = kB * kN;   // 25600
constexpr int kRT = 64;        // k_ff rows per block (4 x 16-row MFMA tiles)
constexpr int kFFBlocks = kNT / kRT;   // 400, exact
constexpr float kEps = 1e-5f;

typedef unsigned short u16;
typedef unsigned int u32;
typedef __attribute__((ext_vector_type(8))) __bf16 bf16x8;
typedef __attribute__((ext_vector_type(4))) float f32x4;
typedef __attribute__((ext_vector_type(8))) unsigned short u16x8;

__device__ __forceinline__ u16 f2bf(float x) {
  __bf16 h = (__bf16)x;                 // native v_cvt (RNE)
  return __builtin_bit_cast(u16, h);
}
__device__ __forceinline__ float bf2f(u16 h) {
  union { u32 u; float f; } v; v.u = ((u32)h) << 16;
  return v.f;
}

// per-channel BN affine from raw (sum, sumsq) stats; stats==nullptr -> identity
__device__ __forceinline__ void affine_from_stats(
    const float* __restrict__ stats, const float* __restrict__ gamma,
    const float* __restrict__ beta, int c, float& sc, float& sh) {
  if (stats != nullptr) {
    float s = stats[c], sq = stats[kC + c];
    float m = s * (1.0f / kNT);
    float v = sq * (1.0f / kNT) - m * m;
    float rs = rsqrtf(v + kEps);
    sc = gamma[c] * rs;
    sh = beta[c] - m * sc;
  } else {
    sc = 1.0f;
    sh = 0.0f;
  }
}

// pack one float4-group g (g < 110592) of {gcn_W, W1, W2} into frag layout.
// frag f; lane l; elem j: B[kb*32 + (l>>4)*8 + j][nb*16 + (l&15)]
//   gcn/W1: f = nb*4 + kb ; W2: f = nb*16 + kb
__device__ __forceinline__ void pack_group(
    int g, const float* __restrict__ gcnW, const float* __restrict__ W1,
    const float* __restrict__ W2, u16* __restrict__ wpack) {
  int layer = g / 36864, r = g % 36864;
  const float* src; int shf; u16* base; int isW2 = 0;
  if (r < 4096) {
    src = gcnW + (size_t)layer * kC * kC; shf = 7;
    base = wpack + (size_t)(layer * 288 + 0) * 512;
  } else if (r < 20480) {
    src = W1 + (size_t)layer * kC * kH; shf = 9;
    base = wpack + (size_t)(layer * 288 + 32) * 512; r -= 4096;
  } else {
    src = W2 + (size_t)layer * kH * kC; shf = 7;
    base = wpack + (size_t)(layer * 288 + 160) * 512; r -= 20480; isW2 = 1;
  }
  int e4 = r * 4;
  int k = e4 >> shf, n0 = e4 & ((1 << shf) - 1);
  float4 v = *(const float4*)(src + ((size_t)k << shf) + n0);
  float vv[4] = {v.x, v.y, v.z, v.w};
  int kb = k >> 5, hi = (k >> 3) & 3, j = k & 7;
#pragma unroll
  for (int t = 0; t < 4; ++t) {
    int n = n0 + t;
    int nb = n >> 4, l = hi * 16 + (n & 15);
    int f = isW2 ? (nb * 16 + kb) : (nb * 4 + kb);
    base[(size_t)f * 512 + l * 8 + j] = f2bf(vv[t]);
  }
}

// ---- fused GCN layer, channel-split: 2 blocks per graph, 64 output channels
// each, 256 threads (4 waves). bf16 activation I/O. FIRST additionally packs
// all weights (one group/thread) and loads its own B-frags strided from raw
// gcn_W. Residual re-read from global bf16 (single rounding).
template <bool FIRST>
__global__ __launch_bounds__(256) void k_gcn(
    const u16* __restrict__ yprev, const float* __restrict__ stats_prev,
    const float* __restrict__ gamma_p, const float* __restrict__ beta_p,
    const u16* __restrict__ Wgp, const float* __restrict__ gb,
    float* __restrict__ stats_out, u16* __restrict__ yA,
    const float* __restrict__ dxy, const float* __restrict__ cxy,
    const float* __restrict__ dem, const float* __restrict__ Wd,
    const float* __restrict__ bd, const float* __restrict__ Wi,
    const float* __restrict__ bi, const float* __restrict__ gcnW,
    const float* __restrict__ W1, const float* __restrict__ W2,
    u16* __restrict__ wpack) {
  __shared__ float s_scale[kC], s_shift[kC];
  __shared__ u16 xs[112][136];       // 30.5 KB, rows >=100 are zero
  __shared__ float hs[kN][68];       // 27.2 KB
  __shared__ float sP[4][64], s_sum[64], s_sq[64];
  __shared__ float scoord[kN][4];    // FIRST only
  __shared__ float swt[7][kC];       // FIRST only
  const int tid = threadIdx.x;
  const int b = blockIdx.x >> 1, half = blockIdx.x & 1;
  const int wave = tid >> 6, lane = tid & 63;
  const int arow = lane & 15, kofs = (lane >> 4) * 8;
  const int crow = (lane >> 4) * 4, ccol = lane & 15;
  const int nbW = half * 4 + wave;
  // B-frags: FIRST loads strided from raw gcn_W layer 0; others load packed.
  bf16x8 bfr[4];
  if (FIRST) {
#pragma unroll
    for (int kb = 0; kb < 4; ++kb)
#pragma unroll
      for (int e = 0; e < 8; ++e) {
        int krow = kb * 32 + (lane >> 4) * 8 + e;
        bfr[kb][e] = (__bf16)gcnW[(size_t)krow * kC + nbW * 16 + (lane & 15)];
      }
  } else {
#pragma unroll
    for (int kb = 0; kb < 4; ++kb)
      bfr[kb] = *(const bf16x8*)(Wgp + (size_t)(nbW * 4 + kb) * 512 + lane * 8);
  }
  if (FIRST) {
    // fold the weight pack into this kernel: one float4-group per thread
    int g = blockIdx.x * 256 + tid;
    if (g < kL * 36864) pack_group(g, gcnW, W1, W2, wpack);
    if (tid < kN) {
      if (tid == 0) {
        scoord[0][0] = dxy[b * 2];
        scoord[0][1] = dxy[b * 2 + 1];
        scoord[0][2] = 0.0f;
      } else {
        int q = b * kNC + tid - 1;
        scoord[tid][0] = cxy[q * 2];
        scoord[tid][1] = cxy[q * 2 + 1];
        scoord[tid][2] = dem[q];
      }
    }
    if (tid < 224) {
      int f = tid * 4, r = f >> 7, c = f & 127;
      const float* s;
      switch (r) {
        case 0: s = Wd + c; break;
        case 1: s = Wd + kC + c; break;
        case 2: s = bd + c; break;
        case 3: s = Wi + c; break;
        case 4: s = Wi + kC + c; break;
        case 5: s = Wi + 2 * kC + c; break;
        default: s = bi + c; break;
      }
      *(float4*)&swt[r][c] = *(const float4*)s;
    }
  }
  if (tid < kC) affine_from_stats(stats_prev, gamma_p, beta_p, tid,
                                  s_scale[tid], s_shift[tid]);
  if (tid < 64) { s_sum[tid] = 0.0f; s_sq[tid] = 0.0f; }
  __syncthreads();
  const size_t gbase = (size_t)b * kN * kC;
  // stage x (BN-affined, bf16) into LDS: 3584 4-channel groups, 14 iters
#pragma unroll
  for (int i = 0; i < 14; ++i) {
    int li = i * 256 + tid;
    int lr = li >> 5, lc = (li & 31) * 4;
    float g0 = 0.f, g1 = 0.f, g2 = 0.f, g3 = 0.f;
    if (lr < kN) {
      if (FIRST) {
        float sx = scoord[lr][0], sy = scoord[lr][1], sd = scoord[lr][2];
        if (lr == 0) {
          g0 = fmaf(sx, swt[0][lc + 0], fmaf(sy, swt[1][lc + 0], swt[2][lc + 0]));
          g1 = fmaf(sx, swt[0][lc + 1], fmaf(sy, swt[1][lc + 1], swt[2][lc + 1]));
          g2 = fmaf(sx, swt[0][lc + 2], fmaf(sy, swt[1][lc + 2], swt[2][lc + 2]));
          g3 = fmaf(sx, swt[0][lc + 3], fmaf(sy, swt[1][lc + 3], swt[2][lc + 3]));
        } else {
          g0 = fmaf(sx, swt[3][lc + 0],
                    fmaf(sy, swt[4][lc + 0], fmaf(sd, swt[5][lc + 0], swt[6][lc + 0])));
          g1 = fmaf(sx, swt[3][lc + 1],
                    fmaf(sy, swt[4][lc + 1], fmaf(sd, swt[5][lc + 1], swt[6][lc + 1])));
          g2 = fmaf(sx, swt[3][lc + 2],
                    fmaf(sy, swt[4][lc + 2], fmaf(sd, swt[5][lc + 2], swt[6][lc + 2])));
          g3 = fmaf(sx, swt[3][lc + 3],
                    fmaf(sy, swt[4][lc + 3], fmaf(sd, swt[5][lc + 3], swt[6][lc + 3])));
        }
      } else {
        ushort4 hv = *(const ushort4*)(yprev + gbase + (size_t)lr * kC + lc);
        g0 = bf2f(hv.x); g1 = bf2f(hv.y); g2 = bf2f(hv.z); g3 = bf2f(hv.w);
      }
    }
    ushort4 h4;
    h4.x = f2bf(fmaf(g0, s_scale[lc + 0], s_shift[lc + 0]));
    h4.y = f2bf(fmaf(g1, s_scale[lc + 1], s_shift[lc + 1]));
    h4.z = f2bf(fmaf(g2, s_scale[lc + 2], s_shift[lc + 2]));
    h4.w = f2bf(fmaf(g3, s_scale[lc + 3], s_shift[lc + 3]));
    *(ushort4*)&xs[lr][lc] = h4;
  }
  __syncthreads();
  // MFMA: wave w owns global col block nbW over all 7 row tiles
  {
#pragma unroll
    for (int t = 0; t < 7; ++t) {
      f32x4 acc = {0.f, 0.f, 0.f, 0.f};
#pragma unroll
      for (int kb = 0; kb < 4; ++kb) {
        bf16x8 a = *(const bf16x8*)&xs[t * 16 + arow][kb * 32 + kofs];
        acc = __builtin_amdgcn_mfma_f32_16x16x32_bf16(a, bfr[kb], acc, 0, 0, 0);
      }
      int rbase = t * 16 + crow;
#pragma unroll
      for (int r = 0; r < 4; ++r)
        if (rbase + r < kN) hs[rbase + r][wave * 16 + ccol] = acc[r];
    }
  }
  __syncthreads();
  // prefix over j (4-way split) for owned 64 channels; residual from global bf16
  const int c = tid & 63, jh = tid >> 6;
  const int ch = half * 64 + c;
  const float sc = s_scale[ch], sh = s_shift[ch];
  const float gbc = gb[ch];
  const int j0 = jh * 25;
  float p = 0.0f;
#pragma unroll
  for (int jj = 0; jj < 25; ++jj)
    p = fmaf(hs[j0 + jj][c], rsqrtf((float)(j0 + jj + 1)), p);
  sP[jh][c] = p;
  __syncthreads();
  float s = 0.0f;
  for (int q = 0; q < jh; ++q) s += sP[q][c];
  float wv0 = 0.f, wv1 = 0.f, wv2 = 0.f, wv3 = 0.f, wd0 = 0.f, wd1 = 0.f, wd2 = 0.f;
  if (FIRST) {
    wv0 = swt[3][ch]; wv1 = swt[4][ch]; wv2 = swt[5][ch]; wv3 = swt[6][ch];
    wd0 = swt[0][ch]; wd1 = swt[1][ch]; wd2 = swt[2][ch];
  }
  float lsum = 0.0f, lsq = 0.0f;
#pragma unroll
  for (int jj = 0; jj < 25; ++jj) {
    int j = j0 + jj;
    float r = rsqrtf((float)(j + 1));
    s = fmaf(hs[j][c], r, s);
    float xv;
    if (FIRST) {
      float sx = scoord[j][0], sy = scoord[j][1], sd = scoord[j][2];
      xv = (j == 0) ? fmaf(sx, wd0, fmaf(sy, wd1, wd2))
                    : fmaf(sx, wv0, fmaf(sy, wv1, fmaf(sd, wv2, wv3)));
    } else {
      xv = fmaf(bf2f(yprev[gbase + (size_t)j * kC + ch]), sc, sh);
    }
    float yv = xv + fmaf(s, r, gbc);
    yA[gbase + (size_t)j * kC + ch] = f2bf(yv);
    lsum += yv;
    lsq = fmaf(yv, yv, lsq);
  }
  atomicAdd(&s_sum[c], lsum);
  atomicAdd(&s_sq[c], lsq);
  __syncthreads();
  if (tid < 64) {
    atomicAdd(&stats_out[half * 64 + tid], s_sum[tid]);
    atomicAdd(&stats_out[kC + half * 64 + tid], s_sq[tid]);
  }
}

// fused FF (MFMA bf16): 64-row tile, 400 blocks (exactly one resident round),
// 8 waves, H-chunked (4 x 128) phase1/phase2 through a small hid buffer.
// bf16 activation I/O; LAST writes f32. Residual loads issued early.
template <bool LAST>
__global__ __launch_bounds__(512, 2) void k_ff(
    const u16* __restrict__ yA, const float* __restrict__ stats_in,
    const float* __restrict__ gamma, const float* __restrict__ beta,
    const u16* __restrict__ W1p, const float* __restrict__ b1,
    const u16* __restrict__ W2p, const float* __restrict__ b2,
    float* __restrict__ stats_out, u16* __restrict__ yB16,
    float* __restrict__ yB32) {
  __shared__ float s_scale[kC], s_shift[kC], s_sum[kC], s_sq[kC];
  __shared__ float s_b1[kH];
  __shared__ u16 xs[kRT][136];       // 17.4 KB
  __shared__ u16 hid[kRT][136];      // 17.4 KB (one 128-H chunk)
  const int tid = threadIdx.x;
  const int wave = tid >> 6, lane = tid & 63;
  const int arow = lane & 15, kofs = (lane >> 4) * 8;
  const int crow = (lane >> 4) * 4, ccol = lane & 15;
  if (tid < kC) {
    affine_from_stats(stats_in, gamma, beta, tid, s_scale[tid], s_shift[tid]);
    s_sum[tid] = 0.0f;
    s_sq[tid] = 0.0f;
  }
  if (tid < 128) ((float4*)s_b1)[tid] = ((const float4*)b1)[tid];
  __syncthreads();
  const int rb = blockIdx.x * kRT;
  // stage: 1024 8-channel groups (16B loads), 2 iters
#pragma unroll
  for (int i = 0; i < 2; ++i) {
    int li = i * 512 + tid;
    int lr = li >> 4, lc8 = (li & 15) * 8;
    u16x8 hv = *(const u16x8*)(yA + (size_t)(rb + lr) * kC + lc8);
    u16x8 o;
#pragma unroll
    for (int e = 0; e < 8; ++e)
      o[e] = f2bf(fmaf(bf2f(hv[e]), s_scale[lc8 + e], s_shift[lc8 + e]));
    *(u16x8*)&xs[lr][lc8] = o;
  }
  // residual loads issued early: global, independent of LDS
  const int c = wave * 16 + ccol;
  u16 resid[16];
#pragma unroll
  for (int rt = 0; rt < 4; ++rt)
#pragma unroll
    for (int r = 0; r < 4; ++r)
      resid[rt * 4 + r] = yA[(size_t)(rb + rt * 16 + crow + r) * kC + c];
  __syncthreads();

  f32x4 oacc[4] = {{0.f, 0.f, 0.f, 0.f}, {0.f, 0.f, 0.f, 0.f},
                   {0.f, 0.f, 0.f, 0.f}, {0.f, 0.f, 0.f, 0.f}};
  for (int chk = 0; chk < 4; ++chk) {
    // W2 frags for this chunk issued early (land during phase 1)
    bf16x8 bw[4];
#pragma unroll
    for (int kb = 0; kb < 4; ++kb)
      bw[kb] = *(const bf16x8*)(W2p + (size_t)(wave * 16 + chk * 4 + kb) * 512 + lane * 8);
    // phase 1: hid[.., chunk] = relu(xs @ W1[:, chunk] + b1); wave -> 16 cols
    const int nb = chk * 8 + wave;
    bf16x8 b1f[4];
#pragma unroll
    for (int kb = 0; kb < 4; ++kb)
      b1f[kb] = *(const bf16x8*)(W1p + (size_t)(nb * 4 + kb) * 512 + lane * 8);
    const float bbias = s_b1[chk * 128 + c];
#pragma unroll
    for (int rt = 0; rt < 4; ++rt) {
      f32x4 acc = {0.f, 0.f, 0.f, 0.f};
#pragma unroll
      for (int kb = 0; kb < 4; ++kb) {
        bf16x8 a = *(const bf16x8*)&xs[rt * 16 + arow][kb * 32 + kofs];
        acc = __builtin_amdgcn_mfma_f32_16x16x32_bf16(a, b1f[kb], acc, 0, 0, 0);
      }
#pragma unroll
      for (int r = 0; r < 4; ++r)
        hid[rt * 16 + crow + r][c] = f2bf(fmaxf(acc[r] + bbias, 0.0f));
    }
    __syncthreads();
    // phase 2: oacc += hid_chunk @ W2[chunk rows][wave's 16 cols]
#pragma unroll
    for (int kb = 0; kb < 4; ++kb) {
#pragma unroll
      for (int rt = 0; rt < 4; ++rt) {
        bf16x8 ha = *(const bf16x8*)&hid[rt * 16 + arow][kb * 32 + kofs];
        oacc[rt] = __builtin_amdgcn_mfma_f32_16x16x32_bf16(ha, bw[kb], oacc[rt], 0, 0, 0);
      }
    }
    __syncthreads();   // before next chunk overwrites hid
  }

  // epilogue: bias + residual, store, BN stats (no tail: 400*64 = 25600)
  const float sc = s_scale[c], sh = s_shift[c], bb = b2[c];
  float psum = 0.0f, psq = 0.0f;
#pragma unroll
  for (int rt = 0; rt < 4; ++rt) {
#pragma unroll
    for (int r = 0; r < 4; ++r) {
      int lrow = rt * 16 + crow + r;
      float xv = fmaf(bf2f(resid[rt * 4 + r]), sc, sh);
      float o = oacc[rt][r] + bb + xv;
      if (LAST)
        yB32[(size_t)(rb + lrow) * kC + c] = o;
      else
        yB16[(size_t)(rb + lrow) * kC + c] = f2bf(o);
      psum += o;
      psq = fmaf(o, o, psq);
    }
  }
  atomicAdd(&s_sum[c], psum);
  atomicAdd(&s_sq[c], psq);
  __syncthreads();
  if (tid < kC) {
    atomicAdd(&stats_out[tid], s_sum[tid]);
    atomicAdd(&stats_out[kC + tid], s_sq[tid]);
  }
}

// final BN apply + nodes out + per-graph mean, 8-way j-split, 1024 threads
__global__ __launch_bounds__(1024) void k_out(
    const float* __restrict__ yB, const float* __restrict__ stats,
    const float* __restrict__ gamma, const float* __restrict__ beta,
    float* __restrict__ out) {
  __shared__ float sP[8][kC];
  const int b = blockIdx.x;
  const int c = threadIdx.x & 127, jh = threadIdx.x >> 7;
  float sc, sh;
  affine_from_stats(stats, gamma, beta, c, sc, sh);
  const int j0 = (jh < 4) ? jh * 13 : 52 + (jh - 4) * 12;
  const int jc = (jh < 4) ? 13 : 12;
  float acc = 0.0f;
  const size_t base = (size_t)b * kN * kC + c;
  for (int jj = 0; jj < jc; ++jj) {
    int j = j0 + jj;
    float xv = fmaf(yB[base + (size_t)j * kC], sc, sh);
    out[base + (size_t)j * kC] = xv;
    acc += xv;
  }
  sP[jh][c] = acc;
  __syncthreads();
  if (jh == 0) {
    float m = 0.0f;
#pragma unroll
    for (int q = 0; q < 8; ++q) m += sP[q][c];
    out[(size_t)kNT * kC + (size_t)b * kC + c] = m * (1.0f / kN);
  }
}

extern "C" void kernel_launch(void* const* d_in, const int* in_sizes, int n_in,
                              void* d_out, int out_size, void* d_ws, size_t ws_size,
                              hipStream_t stream) {
  const float* depot_xy    = (const float*)d_in[0];
  const float* customer_xy = (const float*)d_in[1];
  const float* demand      = (const float*)d_in[2];
  const float* W_depot     = (const float*)d_in[3];
  const float* b_depot     = (const float*)d_in[4];
  const float* W_init      = (const float*)d_in[5];
  const float* b_init      = (const float*)d_in[6];
  const float* gcn_W       = (const float*)d_in[7];
  const float* gcn_b       = (const float*)d_in[8];
  const float* bn_gamma    = (const float*)d_in[9];
  const float* bn_beta     = (const float*)d_in[10];
  const float* ff_W1       = (const float*)d_in[11];
  const float* ff_b1       = (const float*)d_in[12];
  const float* ff_W2       = (const float*)d_in[13];
  const float* ff_b2       = (const float*)d_in[14];

  u16*   yA16  = (u16*)d_ws;                       // NT*kC bf16
  u16*   yB16  = yA16 + (size_t)kNT * kC;          // NT*kC bf16
  float* yB32  = (float*)(yB16 + (size_t)kNT * kC);// NT*kC f32 (last layer)
  float* stats = yB32 + (size_t)kNT * kC;          // 6 x (sum[128], sumsq[128])
  u16*   wpack = (u16*)(stats + kL * 2 * 2 * kC);

  hipMemsetAsync(stats, 0, kL * 2 * 2 * kC * sizeof(float), stream);
  for (int l = 0; l < kL; ++l) {
    const float* sp = (l == 0) ? nullptr : stats + ((l - 1) * 2 + 1) * 2 * kC;
    const float* gp = (l == 0) ? nullptr : bn_gamma + (l - 1) * kC;
    const float* bp = (l == 0) ? nullptr : bn_beta + (l - 1) * kC;
    float* s0 = stats + (l * 2 + 0) * 2 * kC;
    float* s1 = stats + (l * 2 + 1) * 2 * kC;
    const u16* wg  = wpack + (size_t)(l * 288 + 0) * 512;
    const u16* w1p = wpack + (size_t)(l * 288 + 32) * 512;
    const u16* w2p = wpack + (size_t)(l * 288 + 160) * 512;
    if (l == 0) {
      k_gcn<true><<<kB * 2, 256, 0, stream>>>(
          nullptr, sp, gp, bp, nullptr, gcn_b + l * kC, s0, yA16,
          depot_xy, customer_xy, demand, W_depot, b_depot, W_init, b_init,
          gcn_W, ff_W1, ff_W2, wpack);
    } else {
      k_gcn<false><<<kB * 2, 256, 0, stream>>>(
          yB16, sp, gp, bp, wg, gcn_b + l * kC, s0, yA16,
          nullptr, nullptr, nullptr, nullptr, nullptr, nullptr, nullptr,
          nullptr, nullptr, nullptr, nullptr);
    }
    if (l < kL - 1) {
      k_ff<false><<<kFFBlocks, 512, 0, stream>>>(
          yA16, s0, bn_gamma + l * kC, bn_beta + l * kC,
          w1p, ff_b1 + l * kH, w2p, ff_b2 + l * kC, s1, yB16, nullptr);
    } else {
      k_ff<true><<<kFFBlocks, 512, 0, stream>>>(
          yA16, s0, bn_gamma + l * kC, bn_beta + l * kC,
          w1p, ff_b1 + l * kH, w2p, ff_b2 + l * kC, s1, nullptr, yB32);
    }
  }
  k_out<<<kB, 1024, 0, stream>>>(yB32, stats + (2 * 2 + 1) * 2 * kC,
                                 bn_gamma + 2 * kC, bn_beta + 2 * kC, (float*)d_out);
}

// Round 13
// 126.836 us; speedup vs baseline: 1.3137x; 1.0199x over previous
//
#include <hip/hip_runtime.h>

constexpr int kB = 256;
constexpr int kNC = 99;
constexpr int kN = 100;
constexpr int kC = 128;
constexpr int kH = 512;
constexpr int kL = 3;
constexpr int kNT = kB * kN;   // 25600
constexpr int kRT = 64;        // k_ff rows per block (4 x 16-row MFMA tiles)
constexpr int kFFBlocks = kNT / kRT;   // 400, exact
constexpr float kEps = 1e-5f;

typedef unsigned short u16;
typedef unsigned int u32;
typedef __attribute__((ext_vector_type(8))) __bf16 bf16x8;
typedef __attribute__((ext_vector_type(4))) float f32x4;
typedef __attribute__((ext_vector_type(8))) unsigned short u16x8;

__device__ __forceinline__ u16 f2bf(float x) {
  __bf16 h = (__bf16)x;                 // native v_cvt (RNE)
  return __builtin_bit_cast(u16, h);
}
__device__ __forceinline__ float bf2f(u16 h) {
  union { u32 u; float f; } v; v.u = ((u32)h) << 16;
  return v.f;
}

// per-channel BN affine from raw (sum, sumsq) stats; stats==nullptr -> identity
__device__ __forceinline__ void affine_from_stats(
    const float* __restrict__ stats, const float* __restrict__ gamma,
    const float* __restrict__ beta, int c, float& sc, float& sh) {
  if (stats != nullptr) {
    float s = stats[c], sq = stats[kC + c];
    float m = s * (1.0f / kNT);
    float v = sq * (1.0f / kNT) - m * m;
    float rs = rsqrtf(v + kEps);
    sc = gamma[c] * rs;
    sh = beta[c] - m * sc;
  } else {
    sc = 1.0f;
    sh = 0.0f;
  }
}

// pack one float4-group g (g < 110592) of {gcn_W, W1, W2} into frag layout.
// frag f; lane l; elem j: B[kb*32 + (l>>4)*8 + j][nb*16 + (l&15)]
//   gcn/W1: f = nb*4 + kb ; W2: f = nb*16 + kb
__device__ __forceinline__ void pack_group(
    int g, const float* __restrict__ gcnW, const float* __restrict__ W1,
    const float* __restrict__ W2, u16* __restrict__ wpack) {
  int layer = g / 36864, r = g % 36864;
  const float* src; int shf; u16* base; int isW2 = 0;
  if (r < 4096) {
    src = gcnW + (size_t)layer * kC * kC; shf = 7;
    base = wpack + (size_t)(layer * 288 + 0) * 512;
  } else if (r < 20480) {
    src = W1 + (size_t)layer * kC * kH; shf = 9;
    base = wpack + (size_t)(layer * 288 + 32) * 512; r -= 4096;
  } else {
    src = W2 + (size_t)layer * kH * kC; shf = 7;
    base = wpack + (size_t)(layer * 288 + 160) * 512; r -= 20480; isW2 = 1;
  }
  int e4 = r * 4;
  int k = e4 >> shf, n0 = e4 & ((1 << shf) - 1);
  float4 v = *(const float4*)(src + ((size_t)k << shf) + n0);
  float vv[4] = {v.x, v.y, v.z, v.w};
  int kb = k >> 5, hi = (k >> 3) & 3, j = k & 7;
#pragma unroll
  for (int t = 0; t < 4; ++t) {
    int n = n0 + t;
    int nb = n >> 4, l = hi * 16 + (n & 15);
    int f = isW2 ? (nb * 16 + kb) : (nb * 4 + kb);
    base[(size_t)f * 512 + l * 8 + j] = f2bf(vv[t]);
  }
}

// ---- fused GCN layer, channel-split: 2 blocks per graph, 64 output channels
// each, 256 threads (4 waves), 4 blocks/CU (xs and hs UNION one LDS buffer;
// MFMA results held in registers across the transition barrier).
template <bool FIRST>
__global__ __launch_bounds__(256, 4) void k_gcn(
    const u16* __restrict__ yprev, const float* __restrict__ stats_prev,
    const float* __restrict__ gamma_p, const float* __restrict__ beta_p,
    const u16* __restrict__ Wgp, const float* __restrict__ gb,
    float* __restrict__ stats_out, u16* __restrict__ yA,
    const float* __restrict__ dxy, const float* __restrict__ cxy,
    const float* __restrict__ dem, const float* __restrict__ Wd,
    const float* __restrict__ bd, const float* __restrict__ Wi,
    const float* __restrict__ bi, const float* __restrict__ gcnW,
    const float* __restrict__ W1, const float* __restrict__ W2,
    u16* __restrict__ wpack) {
  __shared__ float s_scale[kC], s_shift[kC];
  __shared__ __align__(16) u16 ubuf[112 * 136];   // 30.5 KB: xs, then hs
  __shared__ float sP[4][64], s_sum[64], s_sq[64];
  __shared__ float scoord[kN][4];    // FIRST only
  __shared__ float swt[7][kC];       // FIRST only
  u16 (*xs)[136] = (u16(*)[136])ubuf;
  float* hs = (float*)ubuf;          // stride 68 floats (reused after barrier)
  const int tid = threadIdx.x;
  const int b = blockIdx.x >> 1, half = blockIdx.x & 1;
  const int wave = tid >> 6, lane = tid & 63;
  const int arow = lane & 15, kofs = (lane >> 4) * 8;
  const int crow = (lane >> 4) * 4, ccol = lane & 15;
  const int nbW = half * 4 + wave;
  // B-frags: FIRST loads strided from raw gcn_W layer 0; others load packed.
  bf16x8 bfr[4];
  if (FIRST) {
#pragma unroll
    for (int kb = 0; kb < 4; ++kb)
#pragma unroll
      for (int e = 0; e < 8; ++e) {
        int krow = kb * 32 + (lane >> 4) * 8 + e;
        bfr[kb][e] = (__bf16)gcnW[(size_t)krow * kC + nbW * 16 + (lane & 15)];
      }
  } else {
#pragma unroll
    for (int kb = 0; kb < 4; ++kb)
      bfr[kb] = *(const bf16x8*)(Wgp + (size_t)(nbW * 4 + kb) * 512 + lane * 8);
  }
  if (FIRST) {
    // fold the weight pack into this kernel: one float4-group per thread
    int g = blockIdx.x * 256 + tid;
    if (g < kL * 36864) pack_group(g, gcnW, W1, W2, wpack);
    if (tid < kN) {
      if (tid == 0) {
        scoord[0][0] = dxy[b * 2];
        scoord[0][1] = dxy[b * 2 + 1];
        scoord[0][2] = 0.0f;
      } else {
        int q = b * kNC + tid - 1;
        scoord[tid][0] = cxy[q * 2];
        scoord[tid][1] = cxy[q * 2 + 1];
        scoord[tid][2] = dem[q];
      }
    }
    if (tid < 224) {
      int f = tid * 4, r = f >> 7, c = f & 127;
      const float* s;
      switch (r) {
        case 0: s = Wd + c; break;
        case 1: s = Wd + kC + c; break;
        case 2: s = bd + c; break;
        case 3: s = Wi + c; break;
        case 4: s = Wi + kC + c; break;
        case 5: s = Wi + 2 * kC + c; break;
        default: s = bi + c; break;
      }
      *(float4*)&swt[r][c] = *(const float4*)s;
    }
  }
  if (tid < kC) affine_from_stats(stats_prev, gamma_p, beta_p, tid,
                                  s_scale[tid], s_shift[tid]);
  if (tid < 64) { s_sum[tid] = 0.0f; s_sq[tid] = 0.0f; }
  __syncthreads();
  const size_t gbase = (size_t)b * kN * kC;
  // stage x (BN-affined, bf16) into LDS: 1792 8-channel (16B) groups, 7 iters
#pragma unroll
  for (int i = 0; i < 7; ++i) {
    int li = i * 256 + tid;
    int lr = li >> 4, lc8 = (li & 15) * 8;
    u16x8 o = {0, 0, 0, 0, 0, 0, 0, 0};
    if (lr < kN) {
      if (FIRST) {
        float sx = scoord[lr][0], sy = scoord[lr][1], sd = scoord[lr][2];
#pragma unroll
        for (int e = 0; e < 8; ++e) {
          int c = lc8 + e;
          float g = (lr == 0)
              ? fmaf(sx, swt[0][c], fmaf(sy, swt[1][c], swt[2][c]))
              : fmaf(sx, swt[3][c], fmaf(sy, swt[4][c], fmaf(sd, swt[5][c], swt[6][c])));
          o[e] = f2bf(fmaf(g, s_scale[c], s_shift[c]));
        }
      } else {
        u16x8 hv = *(const u16x8*)(yprev + gbase + (size_t)lr * kC + lc8);
#pragma unroll
        for (int e = 0; e < 8; ++e)
          o[e] = f2bf(fmaf(bf2f(hv[e]), s_scale[lc8 + e], s_shift[lc8 + e]));
      }
    }
    *(u16x8*)&xs[lr][lc8] = o;
  }
  __syncthreads();
  // MFMA into registers: wave w owns global col block nbW over all 7 row tiles
  f32x4 acc[7];
#pragma unroll
  for (int t = 0; t < 7; ++t) {
    acc[t] = {0.f, 0.f, 0.f, 0.f};
#pragma unroll
    for (int kb = 0; kb < 4; ++kb) {
      bf16x8 a = *(const bf16x8*)&xs[t * 16 + arow][kb * 32 + kofs];
      acc[t] = __builtin_amdgcn_mfma_f32_16x16x32_bf16(a, bfr[kb], acc[t], 0, 0, 0);
    }
  }
  __syncthreads();   // all xs reads complete -> reuse buffer as hs
#pragma unroll
  for (int t = 0; t < 7; ++t) {
    int rbase = t * 16 + crow;
#pragma unroll
    for (int r = 0; r < 4; ++r)
      if (rbase + r < kN) hs[(rbase + r) * 68 + wave * 16 + ccol] = acc[t][r];
  }
  __syncthreads();
  // prefix over j (4-way split) for owned 64 channels; residual from global bf16
  const int c = tid & 63, jh = tid >> 6;
  const int ch = half * 64 + c;
  const float sc = s_scale[ch], sh = s_shift[ch];
  const float gbc = gb[ch];
  const int j0 = jh * 25;
  float p = 0.0f;
#pragma unroll
  for (int jj = 0; jj < 25; ++jj)
    p = fmaf(hs[(j0 + jj) * 68 + c], rsqrtf((float)(j0 + jj + 1)), p);
  sP[jh][c] = p;
  __syncthreads();
  float s = 0.0f;
  for (int q = 0; q < jh; ++q) s += sP[q][c];
  float wv0 = 0.f, wv1 = 0.f, wv2 = 0.f, wv3 = 0.f, wd0 = 0.f, wd1 = 0.f, wd2 = 0.f;
  if (FIRST) {
    wv0 = swt[3][ch]; wv1 = swt[4][ch]; wv2 = swt[5][ch]; wv3 = swt[6][ch];
    wd0 = swt[0][ch]; wd1 = swt[1][ch]; wd2 = swt[2][ch];
  }
  float lsum = 0.0f, lsq = 0.0f;
#pragma unroll
  for (int jj = 0; jj < 25; ++jj) {
    int j = j0 + jj;
    float r = rsqrtf((float)(j + 1));
    s = fmaf(hs[j * 68 + c], r, s);
    float xv;
    if (FIRST) {
      float sx = scoord[j][0], sy = scoord[j][1], sd = scoord[j][2];
      xv = (j == 0) ? fmaf(sx, wd0, fmaf(sy, wd1, wd2))
                    : fmaf(sx, wv0, fmaf(sy, wv1, fmaf(sd, wv2, wv3)));
    } else {
      xv = fmaf(bf2f(yprev[gbase + (size_t)j * kC + ch]), sc, sh);
    }
    float yv = xv + fmaf(s, r, gbc);
    yA[gbase + (size_t)j * kC + ch] = f2bf(yv);
    lsum += yv;
    lsq = fmaf(yv, yv, lsq);
  }
  atomicAdd(&s_sum[c], lsum);
  atomicAdd(&s_sq[c], lsq);
  __syncthreads();
  if (tid < 64) {
    atomicAdd(&stats_out[half * 64 + tid], s_sum[tid]);
    atomicAdd(&stats_out[kC + half * 64 + tid], s_sq[tid]);
  }
}

// fused FF (MFMA bf16): 64-row tile, 400 blocks, 8 waves, 2 H-chunks of 256
// (half the barriers of 4x128). VGPR capped at 128 to guarantee 2 blocks/CU.
// bf16 activation I/O; LAST writes f32. Residual loads issued early.
template <bool LAST>
__global__ __launch_bounds__(512, 4) void k_ff(
    const u16* __restrict__ yA, const float* __restrict__ stats_in,
    const float* __restrict__ gamma, const float* __restrict__ beta,
    const u16* __restrict__ W1p, const float* __restrict__ b1,
    const u16* __restrict__ W2p, const float* __restrict__ b2,
    float* __restrict__ stats_out, u16* __restrict__ yB16,
    float* __restrict__ yB32) {
  __shared__ float s_scale[kC], s_shift[kC], s_sum[kC], s_sq[kC];
  __shared__ float s_b1[kH];
  __shared__ u16 xs[kRT][136];       // 17.4 KB
  __shared__ u16 hid[kRT][272];      // 34.8 KB (one 256-H chunk, stride 272)
  const int tid = threadIdx.x;
  const int wave = tid >> 6, lane = tid & 63;
  const int arow = lane & 15, kofs = (lane >> 4) * 8;
  const int crow = (lane >> 4) * 4, ccol = lane & 15;
  if (tid < kC) {
    affine_from_stats(stats_in, gamma, beta, tid, s_scale[tid], s_shift[tid]);
    s_sum[tid] = 0.0f;
    s_sq[tid] = 0.0f;
  }
  if (tid < 128) ((float4*)s_b1)[tid] = ((const float4*)b1)[tid];
  __syncthreads();
  const int rb = blockIdx.x * kRT;
  // stage: 1024 8-channel groups (16B loads), 2 iters
#pragma unroll
  for (int i = 0; i < 2; ++i) {
    int li = i * 512 + tid;
    int lr = li >> 4, lc8 = (li & 15) * 8;
    u16x8 hv = *(const u16x8*)(yA + (size_t)(rb + lr) * kC + lc8);
    u16x8 o;
#pragma unroll
    for (int e = 0; e < 8; ++e)
      o[e] = f2bf(fmaf(bf2f(hv[e]), s_scale[lc8 + e], s_shift[lc8 + e]));
    *(u16x8*)&xs[lr][lc8] = o;
  }
  // residual loads issued early: global, independent of LDS
  const int c = wave * 16 + ccol;
  u16 resid[16];
#pragma unroll
  for (int rt = 0; rt < 4; ++rt)
#pragma unroll
    for (int r = 0; r < 4; ++r)
      resid[rt * 4 + r] = yA[(size_t)(rb + rt * 16 + crow + r) * kC + c];
  __syncthreads();

  f32x4 oacc[4] = {{0.f, 0.f, 0.f, 0.f}, {0.f, 0.f, 0.f, 0.f},
                   {0.f, 0.f, 0.f, 0.f}, {0.f, 0.f, 0.f, 0.f}};
  for (int chk = 0; chk < 2; ++chk) {
    // phase-2 B-frags for this chunk issued early (land during phase 1)
    bf16x8 bw[8];
#pragma unroll
    for (int kk = 0; kk < 8; ++kk)
      bw[kk] = *(const bf16x8*)(W2p + (size_t)(wave * 16 + chk * 8 + kk) * 512 + lane * 8);
    // phase 1: hid[.., 256-chunk] = relu(xs @ W1[:, chunk] + b1)
#pragma unroll
    for (int q = 0; q < 2; ++q) {
      const int nb = chk * 16 + wave * 2 + q;
      bf16x8 b1f[4];
#pragma unroll
      for (int kb = 0; kb < 4; ++kb)
        b1f[kb] = *(const bf16x8*)(W1p + (size_t)(nb * 4 + kb) * 512 + lane * 8);
      const int cl = (wave * 2 + q) * 16 + ccol;           // local col in chunk
      const float bbias = s_b1[chk * 256 + cl];
#pragma unroll
      for (int rt = 0; rt < 4; ++rt) {
        f32x4 acc = {0.f, 0.f, 0.f, 0.f};
#pragma unroll
        for (int kb = 0; kb < 4; ++kb) {
          bf16x8 a = *(const bf16x8*)&xs[rt * 16 + arow][kb * 32 + kofs];
          acc = __builtin_amdgcn_mfma_f32_16x16x32_bf16(a, b1f[kb], acc, 0, 0, 0);
        }
#pragma unroll
        for (int r = 0; r < 4; ++r)
          hid[rt * 16 + crow + r][cl] = f2bf(fmaxf(acc[r] + bbias, 0.0f));
      }
    }
    __syncthreads();
    // phase 2: oacc += hid_chunk @ W2[chunk rows][wave's 16 cols]
#pragma unroll
    for (int kk = 0; kk < 8; ++kk) {
#pragma unroll
      for (int rt = 0; rt < 4; ++rt) {
        bf16x8 ha = *(const bf16x8*)&hid[rt * 16 + arow][kk * 32 + kofs];
        oacc[rt] = __builtin_amdgcn_mfma_f32_16x16x32_bf16(ha, bw[kk], oacc[rt], 0, 0, 0);
      }
    }
    __syncthreads();   // before next chunk overwrites hid
  }

  // epilogue: bias + residual, store, BN stats (no tail: 400*64 = 25600)
  const float sc = s_scale[c], sh = s_shift[c], bb = b2[c];
  float psum = 0.0f, psq = 0.0f;
#pragma unroll
  for (int rt = 0; rt < 4; ++rt) {
#pragma unroll
    for (int r = 0; r < 4; ++r) {
      int lrow = rt * 16 + crow + r;
      float xv = fmaf(bf2f(resid[rt * 4 + r]), sc, sh);
      float o = oacc[rt][r] + bb + xv;
      if (LAST)
        yB32[(size_t)(rb + lrow) * kC + c] = o;
      else
        yB16[(size_t)(rb + lrow) * kC + c] = f2bf(o);
      psum += o;
      psq = fmaf(o, o, psq);
    }
  }
  atomicAdd(&s_sum[c], psum);
  atomicAdd(&s_sq[c], psq);
  __syncthreads();
  if (tid < kC) {
    atomicAdd(&stats_out[tid], s_sum[tid]);
    atomicAdd(&stats_out[kC + tid], s_sq[tid]);
  }
}

// final BN apply + nodes out + per-graph mean, 8-way j-split, 1024 threads
__global__ __launch_bounds__(1024) void k_out(
    const float* __restrict__ yB, const float* __restrict__ stats,
    const float* __restrict__ gamma, const float* __restrict__ beta,
    float* __restrict__ out) {
  __shared__ float sP[8][kC];
  const int b = blockIdx.x;
  const int c = threadIdx.x & 127, jh = threadIdx.x >> 7;
  float sc, sh;
  affine_from_stats(stats, gamma, beta, c, sc, sh);
  const int j0 = (jh < 4) ? jh * 13 : 52 + (jh - 4) * 12;
  const int jc = (jh < 4) ? 13 : 12;
  float acc = 0.0f;
  const size_t base = (size_t)b * kN * kC + c;
  for (int jj = 0; jj < jc; ++jj) {
    int j = j0 + jj;
    float xv = fmaf(yB[base + (size_t)j * kC], sc, sh);
    out[base + (size_t)j * kC] = xv;
    acc += xv;
  }
  sP[jh][c] = acc;
  __syncthreads();
  if (jh == 0) {
    float m = 0.0f;
#pragma unroll
    for (int q = 0; q < 8; ++q) m += sP[q][c];
    out[(size_t)kNT * kC + (size_t)b * kC + c] = m * (1.0f / kN);
  }
}

extern "C" void kernel_launch(void* const* d_in, const int* in_sizes, int n_in,
                              void* d_out, int out_size, void* d_ws, size_t ws_size,
                              hipStream_t stream) {
  const float* depot_xy    = (const float*)d_in[0];
  const float* customer_xy = (const float*)d_in[1];
  const float* demand      = (const float*)d_in[2];
  const float* W_depot     = (const float*)d_in[3];
  const float* b_depot     = (const float*)d_in[4];
  const float* W_init      = (const float*)d_in[5];
  const float* b_init      = (const float*)d_in[6];
  const float* gcn_W       = (const float*)d_in[7];
  const float* gcn_b       = (const float*)d_in[8];
  const float* bn_gamma    = (const float*)d_in[9];
  const float* bn_beta     = (const float*)d_in[10];
  const float* ff_W1       = (const float*)d_in[11];
  const float* ff_b1       = (const float*)d_in[12];
  const float* ff_W2       = (const float*)d_in[13];
  const float* ff_b2       = (const float*)d_in[14];

  u16*   yA16  = (u16*)d_ws;                       // NT*kC bf16
  u16*   yB16  = yA16 + (size_t)kNT * kC;          // NT*kC bf16
  float* yB32  = (float*)(yB16 + (size_t)kNT * kC);// NT*kC f32 (last layer)
  float* stats = yB32 + (size_t)kNT * kC;          // 6 x (sum[128], sumsq[128])
  u16*   wpack = (u16*)(stats + kL * 2 * 2 * kC);

  hipMemsetAsync(stats, 0, kL * 2 * 2 * kC * sizeof(float), stream);
  for (int l = 0; l < kL; ++l) {
    const float* sp = (l == 0) ? nullptr : stats + ((l - 1) * 2 + 1) * 2 * kC;
    const float* gp = (l == 0) ? nullptr : bn_gamma + (l - 1) * kC;
    const float* bp = (l == 0) ? nullptr : bn_beta + (l - 1) * kC;
    float* s0 = stats + (l * 2 + 0) * 2 * kC;
    float* s1 = stats + (l * 2 + 1) * 2 * kC;
    const u16* wg  = wpack + (size_t)(l * 288 + 0) * 512;
    const u16* w1p = wpack + (size_t)(l * 288 + 32) * 512;
    const u16* w2p = wpack + (size_t)(l * 288 + 160) * 512;
    if (l == 0) {
      k_gcn<true><<<kB * 2, 256, 0, stream>>>(
          nullptr, sp, gp, bp, nullptr, gcn_b + l * kC, s0, yA16,
          depot_xy, customer_xy, demand, W_depot, b_depot, W_init, b_init,
          gcn_W, ff_W1, ff_W2, wpack);
    } else {
      k_gcn<false><<<kB * 2, 256, 0, stream>>>(
          yB16, sp, gp, bp, wg, gcn_b + l * kC, s0, yA16,
          nullptr, nullptr, nullptr, nullptr, nullptr, nullptr, nullptr,
          nullptr, nullptr, nullptr, nullptr);
    }
    if (l < kL - 1) {
      k_ff<false><<<kFFBlocks, 512, 0, stream>>>(
          yA16, s0, bn_gamma + l * kC, bn_beta + l * kC,
          w1p, ff_b1 + l * kH, w2p, ff_b2 + l * kC, s1, yB16, nullptr);
    } else {
      k_ff<true><<<kFFBlocks, 512, 0, stream>>>(
          yA16, s0, bn_gamma + l * kC, bn_beta + l * kC,
          w1p, ff_b1 + l * kH, w2p, ff_b2 + l * kC, s1, nullptr, yB32);
    }
  }
  k_out<<<kB, 1024, 0, stream>>>(yB32, stats + (2 * 2 + 1) * 2 * kC,
                                 bn_gamma + 2 * kC, bn_beta + 2 * kC, (float*)d_out);
}